// Round 6
// baseline (2767.047 us; speedup 1.0000x reference)
//
#include <hip/hip_runtime.h>

// ---------------------------------------------------------------------------
// SimpleGRU on MI355X (gfx950). Round 11: L1-invalidate XCD-local detection.
//   r9/r10 (PASS, 2.13ms; rec 3.88us/step IDENTICAL): any detection through
//   the device coherence fabric costs ~3us under 256-wave polling (r6/r8/r9/
//   r10 all land 3.9-5.5us/step). Producer+consumer share the XCD L2; plain
//   stores land there (vmcnt ack = L2). Same-L2 polling failed before ONLY
//   because repeated polls were served by the consumer's stale L1 (one-shot
//   first-touch reads always worked). Fix: acquire-agent fence (emits
//   buffer_inv; compile-safe builtin) between polls -> plain load misses L1,
//   reads the dirty flag line in the shared L2. Detection ~400cy, no fabric.
//   Release: plain fast-data stores -> vmcnt(0) -> plain flags_l -> sc0sc1
//   flags_s -> sc0sc1 truth (system fallbacks stay fed).
//   Ladder: LOCAL gate >3000 rounds -> sticky SYS gate (=r10, 3.88us/step);
//   sentinel one-shot -> truth poll; >=8 bad steps -> TRUTH-only (=r6);
//   non-32/XCD dispatch -> literal r6 fallback.
// ws: xg bf16 [512][1536][64] | truth [depth][64][512] f16 |
//     fast [8][depth][8][512] f16 | prog int[512] | flag_s int[8][32] |
//     flag_l int[8][64] (256B/group, line-isolated)
// ---------------------------------------------------------------------------

typedef unsigned short ushort_t;
typedef short short8      __attribute__((ext_vector_type(8)));
typedef float floatx4     __attribute__((ext_vector_type(4)));
typedef unsigned int uintx4 __attribute__((ext_vector_type(4)));
typedef unsigned short ushort4v __attribute__((ext_vector_type(4)));
typedef _Float16 half8    __attribute__((ext_vector_type(8)));

#define SEQL 512
#define BATCH 64
#define EMBD 256
#define HID 512
#define G3 1536
#define NOUT 5
#define NGRP 8                     // one group per XCD (fast mode)
#define GRPB 8                     // batches per group (fast mode)
#define GSLOT 8192                 // fast ring slot: 8 x 512 x 2B
#define TSLOT 65536                // truth ring slot: 64 x 512 x 2B
#define RING2 131072               // truth + fast bytes per depth unit
#define XG_BYTES 100663296
#define PROGN 512                  // legacy prog area (includes regs at 384)
#define FLAGN 256                  // flag_s[8][32]
#define FLAG2N 512                 // flag_l[8][64] (padded to 256B/group)
#define ZERON (PROGN + FLAGN + FLAG2N)
#define BAD_LIMIT 8
#define POLL_BUDGET 3000

__device__ __forceinline__ float bf2f(ushort_t v){
  union { unsigned u; float f; } x; x.u = ((unsigned)v) << 16; return x.f;
}
__device__ __forceinline__ ushort_t f2bf(float f){
  unsigned u = __float_as_uint(f);
  return (ushort_t)((u + 0x7FFFu + ((u >> 16) & 1u)) >> 16);
}
__device__ __forceinline__ float sigm(float x){
  x = fminf(fmaxf(x, -20.f), 20.f);
  return 1.f / (1.f + __expf(-x));
}
__device__ __forceinline__ float tanh_c(float x){
  x = fminf(fmaxf(x, -10.f), 10.f);
  float e = __expf(2.f * x);
  return (e - 1.f) / (e + 1.f);
}
__device__ __forceinline__ bool has_sent(half8 v){
  union { half8 h; unsigned u[4]; } x; x.h = v;
  bool b = false;
  #pragma unroll
  for (int i = 0; i < 4; ++i){
    b |= ((x.u[i] & 0xFFFFu) == 0xFFFFu);
    b |= ((x.u[i] >> 16) == 0xFFFFu);
  }
  return b;
}

// --- K0: sentinel-fill both rings at SYSTEM scope; zero prog+flags. ---
__global__ __launch_bounds__(256) void gru_init(char* __restrict__ rings,
                                                int* __restrict__ prog){
  size_t i = ((size_t)blockIdx.x * 256 + threadIdx.x) * 16;
  uintx4 s = {0xFFFFFFFFu, 0xFFFFFFFFu, 0xFFFFFFFFu, 0xFFFFFFFFu};
  const char* p = rings + i;
  asm volatile("global_store_dwordx4 %0, %1, off sc0 sc1" :: "v"(p), "v"(s) : "memory");
  if (blockIdx.x == 0){
    int z = 0;
    for (int k = threadIdx.x; k < ZERON; k += 256){
      asm volatile("global_store_dword %0, %1, off sc0 sc1"
                   :: "v"(prog + k), "v"(z) : "memory");
    }
  }
}

// --- K1: x_gates = emb[seq] @ w_ih^T + b_ih, bf16, layout [s][1536][64] ---
#define LDSIDX2(row, chunk) (((row) << 7) + ((((chunk) ^ ((row) & 7))) << 3))
__global__ __launch_bounds__(256) void gru_xgates(
    const int* __restrict__ seq, const float* __restrict__ emb,
    const float* __restrict__ w_ih, const float* __restrict__ b_ih,
    ushort_t* __restrict__ xg)
{
  __shared__ __align__(16) short lA[64 * 128];
  __shared__ __align__(16) short lB[64 * 128];
  const int tid   = threadIdx.x;
  const int sIdx  = blockIdx.x;
  const int nBase = blockIdx.y * 64;
  const int w    = tid >> 6;
  const int l    = tid & 63;
  const int l15  = l & 15;
  const int quad = l >> 4;
  floatx4 acc[4] = {};

  #pragma unroll
  for (int kp = 0; kp < 2; ++kp){
    __syncthreads();
    #pragma unroll
    for (int i = 0; i < 4; ++i){
      int lin = i * 256 + tid;
      int row = lin >> 4;
      int kc  = lin & 15;
      int kbase = kp * 128 + kc * 8;
      int token = seq[(sIdx << 6) + row];
      const float* srcA = emb  + (size_t)token * EMBD + kbase;
      const float* srcB = w_ih + (size_t)(nBase + row) * EMBD + kbase;
      floatx4 a0 = *(const floatx4*)(srcA);
      floatx4 a1 = *(const floatx4*)(srcA + 4);
      floatx4 b0 = *(const floatx4*)(srcB);
      floatx4 b1 = *(const floatx4*)(srcB + 4);
      short8 pa, pb;
      #pragma unroll
      for (int j = 0; j < 4; ++j){
        pa[j]     = (short)f2bf(a0[j]);
        pa[j + 4] = (short)f2bf(a1[j]);
        pb[j]     = (short)f2bf(b0[j]);
        pb[j + 4] = (short)f2bf(b1[j]);
      }
      *(short8*)&lA[LDSIDX2(row, kc)] = pa;
      *(short8*)&lB[LDSIDX2(row, kc)] = pb;
    }
    __syncthreads();
    #pragma unroll
    for (int kc = 0; kc < 4; ++kc){
      int chunk = kc * 4 + quad;
      short8 a = *(const short8*)&lA[LDSIDX2(w * 16 + l15, chunk)];
      #pragma unroll
      for (int s = 0; s < 4; ++s){
        short8 bf = *(const short8*)&lB[LDSIDX2(s * 16 + l15, chunk)];
        acc[s] = __builtin_amdgcn_mfma_f32_16x16x32_bf16(a, bf, acc[s], 0, 0, 0);
      }
    }
  }
  #pragma unroll
  for (int s = 0; s < 4; ++s){
    int g = nBase + s * 16 + l15;
    float bias = b_ih[g];
    ushort4v pk;
    #pragma unroll
    for (int r = 0; r < 4; ++r) pk[r] = f2bf(acc[s][r] + bias);
    *(ushort4v*)(xg + ((size_t)sIdx * G3 + g) * BATCH + (w * 16 + quad * 4)) = pk;
  }
}

// --- K2: recurrence. 256 blocks x 256 threads. ---
__global__ __launch_bounds__(256, 1) void gru_rec(
    const ushort_t* __restrict__ xg, const float* __restrict__ whh,
    const float* __restrict__ bhh, const int* __restrict__ lengths,
    char* __restrict__ truth, char* __restrict__ fastr,
    int* __restrict__ prog, int depth)
{
  __shared__ __align__(16) _Float16 wlds[48 * 64 * 8];   // 49,152 B (B-frags)
  __shared__ __align__(16) _Float16 hscr[4 * 256];       //  2,048 B (repack)
  __shared__ int s_grp, s_slc, s_fast;
  const int tid  = threadIdx.x;
  const int w    = tid >> 6;
  const int l    = tid & 63;
  const int l15  = l & 15;
  const int quad = l >> 4;
  int* flags_s = prog + PROGN;           // [NGRP][32] system-scope flags
  int* flags_l = prog + PROGN + FLAGN;   // [NGRP][64] XCD-local flags

  // ---- rendezvous + XCD-affinity group formation ----
  int* regs = prog + 384;              // [0]=gcount, [1..8]=per-XCD counts
  if (tid == 0){
    unsigned xcd;
    asm volatile("s_getreg_b32 %0, hwreg(HW_REG_XCC_ID)" : "=s"(xcd));
    xcd &= 7u;
    int myx = atomicAdd(&regs[1 + xcd], 1);
    asm volatile("s_waitcnt vmcnt(0)" ::: "memory");  // xcd count visible first
    int gt = atomicAdd(&regs[0], 1);
    int v;
    do {
      asm volatile("s_sleep 1" ::: "memory");
      asm volatile("global_load_dword %0, %1, off sc0 sc1\n\t"
                   "s_waitcnt vmcnt(0)"
                   : "=v"(v) : "v"(&regs[0]) : "memory");
    } while (v < 256);
    int ok = 1;
    #pragma unroll
    for (int x = 0; x < 8; ++x){
      int c;
      asm volatile("global_load_dword %0, %1, off sc0 sc1\n\t"
                   "s_waitcnt vmcnt(0)"
                   : "=v"(c) : "v"(&regs[1 + x]) : "memory");
      ok &= (c == 32);
    }
    s_fast = ok;
    s_grp  = ok ? (int)xcd : 0;
    s_slc  = ok ? (myx & 31) : gt;
  }
  __syncthreads();
  const int fast = s_fast;
  const int grp  = s_grp;
  const int g0   = s_slc;
  if (!fast && g0 >= 32) return;       // fallback: only 32 blocks participate
  const int g = g0 & 31;               // hidden slice [g*16, g*16+16)
  const int j = g * 16 + l15;          // this lane's hidden unit

  // ---- setup: 48 W_hh rows f32->f16 into B-frag LDS (all 4 waves) ----
  #pragma unroll
  for (int i = 0; i < 12; ++i){
    int p  = i * 4 + w;                 // 0..47
    int G  = p >> 4;                    // gate (0=r,1=z,2=n)
    int ks = p & 15;                    // K-step
    const float* src = whh + (size_t)(G * HID + j) * HID + ks * 32 + quad * 8;
    floatx4 f0 = *(const floatx4*)(src);
    floatx4 f1 = *(const floatx4*)(src + 4);
    half8 hv;
    #pragma unroll
    for (int q = 0; q < 4; ++q){ hv[q] = (_Float16)f0[q]; hv[q + 4] = (_Float16)f1[q]; }
    *(half8*)&wlds[((size_t)p * 64 + l) * 8] = hv;
  }
  __syncthreads();
  if (fast && tid >= 64) return;       // fast mode: wave 0 runs alone

  char* fastb = fastr + (size_t)grp * depth * GSLOT;
  const int locb = fast ? ((quad & 1) * 4) : (quad * 4);  // wave-local batch base
  const int gb   = fast ? (grp * GRPB + locb) : (w * 16 + locb);  // global batch
  const int arow = l15 & 7;                                // fast ring A-row
  const int trow = fast ? (grp * GRPB + (l15 & 7)) : (w * 16 + l15); // truth row
  const float bhR = bhh[j], bhZ = bhh[HID + j], bhN = bhh[2 * HID + j];
  int   len[4];
  float h[4];
  #pragma unroll
  for (int r = 0; r < 4; ++r){ len[r] = lengths[gb + r]; h[r] = 0.f; }
  const int Lmax  = lengths[0];        // global max: all blocks run to Lmax
  const int mask  = depth - 1;
  const bool reuse = (depth < Lmax);
  const int flagmode = fast && !reuse; // flag-released L2 exchange
  const int* fpoll_s = flags_s + grp * 32 + (l & 31);
  int* fpub_s = flags_s + grp * 32 + g;
  const int* fpoll_l = flags_l + grp * 64 + (l & 31);
  int* fpub_l = flags_l + grp * 64 + g;
  int cmin = 0;
  int badcnt = 0;
  // mode: 2 = LOCAL gate (fence+L2), 1 = SYS gate (sc0sc1), 0 = TRUTH only
  int mode = flagmode ? 2 : 0;

  for (int t = 0; t < Lmax; ++t){
    // 0) ring-reuse guard (legacy modes only; dead when depth >= Lmax)
    if (reuse && t >= depth){
      int target = t - depth + 2;
      if (cmin < target){
        int tgt2 = target + 4;
        if (fast){
          const int* pp = prog + 128 + grp * 32 + (l & 31);
          while (true){
            int p0;
            asm volatile("global_load_dword %0, %1, off sc0 sc1\n\t"
                         "s_waitcnt vmcnt(0)"
                         : "=v"(p0) : "v"(pp) : "memory");
            if (__all(p0 >= tgt2)) break;
            __builtin_amdgcn_s_sleep(2);
          }
        } else {
          while (true){
            int p0, p1;
            asm volatile("global_load_dword %0, %2, off sc0 sc1\n\t"
                         "global_load_dword %1, %3, off sc0 sc1\n\t"
                         "s_waitcnt vmcnt(0)"
                         : "=v"(p0), "=v"(p1) : "v"(prog + l), "v"(prog + 64 + l)
                         : "memory");
            if (__all(p0 >= tgt2 && p1 >= tgt2)) break;
            __builtin_amdgcn_s_sleep(2);
          }
        }
        cmin = tgt2;
      }
    }

    // 1) xg prefetch (independent of h)
    const ushort_t* xt = xg + (size_t)t * G3 * BATCH;
    ushort4v xR = __builtin_nontemporal_load(
        (const ushort4v*)(xt + (size_t)(          j) * BATCH + gb));
    ushort4v xZ = __builtin_nontemporal_load(
        (const ushort4v*)(xt + (size_t)(HID     + j) * BATCH + gb));
    ushort4v xN = __builtin_nontemporal_load(
        (const ushort4v*)(xt + (size_t)(2 * HID + j) * BATCH + gb));

    // 2) consume h(t-1)
    floatx4 aR = {0.f,0.f,0.f,0.f}, aZ = {0.f,0.f,0.f,0.f}, aN = {0.f,0.f,0.f,0.f};
    if (t > 0){
      const int slotp = (t - 1) & mask;
      const char* rowf = fastb + (size_t)slotp * GSLOT
                       + (size_t)arow * 1024 + quad * 16;
      const char* rowt = truth + (size_t)slotp * TSLOT
                       + (size_t)trow * 1024 + quad * 16;
      half8 aF[16];
      bool have = false;
      if (mode == 2){
        // 2a-LOCAL: acquire-agent fence invalidates this CU's L1 -> plain
        //     load reads the dirty flag line in the SHARED XCD L2. No fabric.
        int miss = 0;
        while (true){
          __builtin_amdgcn_fence(__ATOMIC_ACQUIRE, "agent");
          int fv;
          asm volatile("global_load_dword %0, %1, off\n\t"
                       "s_waitcnt vmcnt(0)"
                       : "=v"(fv) : "v"(fpoll_l) : "memory");
          if (__all(fv >= t)) break;
          if (++miss > POLL_BUDGET){ mode = 1; break; }  // sticky downgrade
        }
      }
      if (mode == 1){
        // 2a-SYS: r10-proven system-scope flag gate
        int miss = 0;
        while (true){
          int fv;
          asm volatile("global_load_dword %0, %1, off sc0 sc1\n\t"
                       "s_waitcnt vmcnt(0)"
                       : "=v"(fv) : "v"(fpoll_s) : "memory");
          if (__all(fv >= t)) break;
          ++miss;
          if (miss > 64) __builtin_amdgcn_s_sleep(8);
          else           __builtin_amdgcn_s_sleep(1);
        }
      }
      if (mode >= 1){
        // 2b: one-shot data read from the shared XCD L2 (first touch of this
        //     address by this block; L1 also freshly invalidated in LOCAL)
        #pragma unroll
        for (int ks = 0; ks < 16; ++ks){
          const char* pa = rowf + ks * 64;
          asm volatile("global_load_dwordx4 %0, %1, off sc0"
                       : "=v"(aF[ks]) : "v"(pa) : "memory");
        }
        asm volatile("s_waitcnt vmcnt(0)"
                     : "+v"(aF[0]),  "+v"(aF[1]),  "+v"(aF[2]),  "+v"(aF[3]),
                       "+v"(aF[4]),  "+v"(aF[5]),  "+v"(aF[6]),  "+v"(aF[7]),
                       "+v"(aF[8]),  "+v"(aF[9]),  "+v"(aF[10]), "+v"(aF[11]),
                       "+v"(aF[12]), "+v"(aF[13]), "+v"(aF[14]), "+v"(aF[15])
                     :: "memory");
        bool bad = false;
        #pragma unroll
        for (int ks = 0; ks < 16; ++ks) bad |= has_sent(aF[ks]);
        have = !__any(bad);
        if (!have && ++badcnt >= BAD_LIMIT) mode = 0;
      }
      if (!have){
        // legacy / escalation: self-synchronizing sentinel poll on truth
        int rounds = 0;
        while (true){
          if (rounds){
            if (rounds > 64) __builtin_amdgcn_s_sleep(8);
            else             __builtin_amdgcn_s_sleep(2);
          }
          ++rounds;
          #pragma unroll
          for (int ks = 0; ks < 16; ++ks){
            const char* pa = rowt + ks * 64;
            asm volatile("global_load_dwordx4 %0, %1, off sc0 sc1"
                         : "=v"(aF[ks]) : "v"(pa) : "memory");
          }
          asm volatile("s_waitcnt vmcnt(0)"
                       : "+v"(aF[0]),  "+v"(aF[1]),  "+v"(aF[2]),  "+v"(aF[3]),
                         "+v"(aF[4]),  "+v"(aF[5]),  "+v"(aF[6]),  "+v"(aF[7]),
                         "+v"(aF[8]),  "+v"(aF[9]),  "+v"(aF[10]), "+v"(aF[11]),
                         "+v"(aF[12]), "+v"(aF[13]), "+v"(aF[14]), "+v"(aF[15])
                       :: "memory");
          bool bad = false;
          #pragma unroll
          for (int ks = 0; ks < 16; ++ks) bad |= has_sent(aF[ks]);
          if (!__any(bad)) break;
        }
      }
      #pragma unroll
      for (int ks = 0; ks < 16; ++ks){
        half8 a  = aF[ks];
        half8 b0 = *(const half8*)&wlds[((size_t)(0 * 16 + ks) * 64 + l) * 8];
        half8 b1 = *(const half8*)&wlds[((size_t)(1 * 16 + ks) * 64 + l) * 8];
        half8 b2 = *(const half8*)&wlds[((size_t)(2 * 16 + ks) * 64 + l) * 8];
        aR = __builtin_amdgcn_mfma_f32_16x16x32_f16(a, b0, aR, 0, 0, 0);
        aZ = __builtin_amdgcn_mfma_f32_16x16x32_f16(a, b1, aZ, 0, 0, 0);
        aN = __builtin_amdgcn_mfma_f32_16x16x32_f16(a, b2, aN, 0, 0, 0);
      }
      // restore sentinels on consumed truth chunks (legacy reuse only)
      if (reuse){
        uintx4 sv = {0xFFFFFFFFu, 0xFFFFFFFFu, 0xFFFFFFFFu, 0xFFFFFFFFu};
        if (!fast || l15 < 8){
          #pragma unroll
          for (int ks = 0; ks < 16; ++ks){
            const char* pt = rowt + ks * 64;
            asm volatile("global_store_dwordx4 %0, %1, off sc0 sc1"
                         :: "v"(pt), "v"(sv) : "memory");
          }
        }
      }
    }

    // 3) gates + h update (f32 carry); mirrored quads duplicate harmlessly
    #pragma unroll
    for (int r = 0; r < 4; ++r){
      float rr = sigm(bf2f(xR[r]) + aR[r] + bhR);
      float zz = sigm(bf2f(xZ[r]) + aZ[r] + bhZ);
      float nn = tanh_c(bf2f(xN[r]) + rr * (aN[r] + bhN));
      float hn = (1.f - zz) * nn + zz * h[r];
      h[r] = (t < len[r]) ? hn : h[r];
    }

    // 4) intra-wave repack via LDS, then publish h(t)
    _Float16* scr = hscr + w * 256;
    if (!fast || quad < 2){
      #pragma unroll
      for (int r = 0; r < 4; ++r) scr[(locb + r) * 16 + l15] = (_Float16)h[r];
    }
    asm volatile("s_waitcnt lgkmcnt(0)" ::: "memory");   // wave-local DS order
    if (flagmode){
      // release: PLAIN fast-data stores (write-through into own XCD L2) ->
      // vmcnt ack -> PLAIN local flag -> sc0sc1 system flag -> sc0sc1 truth
      if (l < 16){
        int bl = l >> 1;
        int hc = l & 1;
        half8 ch = *(const half8*)&scr[bl * 16 + hc * 8];
        const char* df = fastb + (size_t)(t & mask) * GSLOT
                       + (size_t)bl * 1024 + (size_t)g * 32 + (size_t)hc * 16;
        asm volatile("global_store_dwordx4 %0, %1, off"
                     :: "v"(df), "v"(ch) : "memory");
      }
      asm volatile("s_waitcnt vmcnt(0)" ::: "memory");   // data in XCD L2
      if (l == 0){
        int pv = t + 1;
        asm volatile("global_store_dword %0, %1, off"
                     :: "v"(fpub_l), "v"(pv) : "memory");
        asm volatile("global_store_dword %0, %1, off sc0 sc1"
                     :: "v"(fpub_s), "v"(pv) : "memory");
      }
      if (l < 16){
        int bl = l >> 1;
        int hc = l & 1;
        half8 ch = *(const half8*)&scr[bl * 16 + hc * 8];
        const char* dt = truth + (size_t)(t & mask) * TSLOT
                       + (size_t)(grp * GRPB + bl) * 1024
                       + (size_t)g * 32 + (size_t)hc * 16;
        asm volatile("global_store_dwordx4 %0, %1, off sc0 sc1"
                     :: "v"(dt), "v"(ch) : "memory");
      }
    } else {
      const int pubN = fast ? 16 : 32;
      if (l < pubN){
        int bl = l >> 1;
        int hc = l & 1;
        half8 ch = *(const half8*)&scr[bl * 16 + hc * 8];
        int gbatch = fast ? (grp * GRPB + bl) : (w * 16 + bl);
        const char* dt = truth + (size_t)(t & mask) * TSLOT
                       + (size_t)gbatch * 1024 + (size_t)g * 32 + (size_t)hc * 16;
        asm volatile("global_store_dwordx4 %0, %1, off sc0 sc1"
                     :: "v"(dt), "v"(ch) : "memory");
      }
      // 5) coarse progress publish (reuse mode only), ordered after restores
      if (reuse && ((t & 7) == 7)){
        asm volatile("s_waitcnt vmcnt(0)" ::: "memory");
        if (l == 0){
          int pv = t + 1;
          const int* pp = fast ? (prog + 128 + grp * 32 + g) : (prog + w * 32 + g);
          asm volatile("global_store_dword %0, %1, off sc0 sc1"
                       :: "v"(pp), "v"(pv) : "memory");
        }
      }
    }
  }
}

// --- K3: logits + log_softmax from truth slot (Lmax-1). 64 blocks x 64. ---
__global__ __launch_bounds__(64) void gru_out(
    const char* __restrict__ truth, const int* __restrict__ lengths,
    const float* __restrict__ wout, const float* __restrict__ bout,
    float* __restrict__ out, int depth)
{
  const int b = blockIdx.x, l = threadIdx.x;
  const int Lmax = lengths[0];
  const _Float16* h = (const _Float16*)(truth
      + (size_t)((Lmax - 1) & (depth - 1)) * TSLOT + (size_t)b * 1024);
  half8 hv = *(const half8*)(h + l * 8);
  float p[NOUT];
  #pragma unroll
  for (int o = 0; o < NOUT; ++o){
    const float* wr = wout + o * HID + l * 8;
    float a = 0.f;
    #pragma unroll
    for (int i = 0; i < 8; ++i) a += wr[i] * (float)hv[i];
    #pragma unroll
    for (int d = 32; d >= 1; d >>= 1) a += __shfl_down(a, d, 64);
    p[o] = a;
  }
  if (l == 0){
    float lg[NOUT], m = -1e30f;
    #pragma unroll
    for (int o = 0; o < NOUT; ++o){
      float v = p[o] + bout[o];
      if (!(v == v)) v = -1.0f;
      lg[o] = v; m = fmaxf(m, v);
    }
    float ssum = 0.f;
    #pragma unroll
    for (int o = 0; o < NOUT; ++o) ssum += __expf(lg[o] - m);
    float ls = __logf(ssum);
    #pragma unroll
    for (int o = 0; o < NOUT; ++o) out[b * NOUT + o] = lg[o] - m - ls;
  }
}

extern "C" void kernel_launch(void* const* d_in, const int* in_sizes, int n_in,
                              void* d_out, int out_size, void* d_ws, size_t ws_size,
                              hipStream_t stream) {
  (void)in_sizes; (void)n_in; (void)out_size;
  const int*   seq     = (const int*)d_in[0];
  const int*   lengths = (const int*)d_in[1];
  const float* emb     = (const float*)d_in[2];
  const float* w_ih    = (const float*)d_in[3];
  const float* w_hh    = (const float*)d_in[4];
  const float* b_ih    = (const float*)d_in[5];
  const float* b_hh    = (const float*)d_in[6];
  const float* w_out   = (const float*)d_in[7];
  const float* b_out   = (const float*)d_in[8];
  float*       outp    = (float*)d_out;

  // ring depth: largest power of two in [16, 512] such that both rings
  // (depth * 128 KiB) + prog/flags fit the workspace after xg.
  size_t avail = (ws_size > (size_t)XG_BYTES + 32768)
               ? ws_size - (size_t)XG_BYTES - 32768 : 0;
  int depth = 16;
  while (depth < 512 && ((size_t)(depth << 1) * RING2) <= avail) depth <<= 1;

  char* ws = (char*)d_ws;
  ushort_t* xg    = (ushort_t*)ws;                                 // 100,663,296 B
  char*     truth = ws + XG_BYTES;                                 // depth*65,536 B
  char*     fastr = truth + (size_t)depth * TSLOT;                 // depth*65,536 B
  int*      prog  = (int*)(fastr + (size_t)depth * TSLOT);         // 1280 ints

  gru_init<<<depth * 32, 256, 0, stream>>>(truth, prog);
  dim3 g1(SEQL, G3 / 64);
  gru_xgates<<<g1, 256, 0, stream>>>(seq, emb, w_ih, b_ih, xg);
  gru_rec<<<256, 256, 0, stream>>>(xg, w_hh, b_hh, lengths, truth, fastr, prog, depth);
  gru_out<<<BATCH, 64, 0, stream>>>(truth, lengths, w_out, b_out, outp, depth);
}

// Round 7
// 2246.973 us; speedup vs baseline: 1.2315x; 1.2315x over previous
//
#include <hip/hip_runtime.h>

// ---------------------------------------------------------------------------
// SimpleGRU on MI355X (gfx950). Round 12: buffer_inv sc0 XCD-local detection.
//   r10 (PASS, rec 3.88us/step): system-scope flag gate; fabric RT floor.
//   r11 (PASS, rec 5.08us/step): acquire-AGENT fence emits buffer_inv sc1 ->
//     invalidates the shared L2 TOO -> polls went back through the fabric,
//     plus 3000-round budget burn -> slower. Diagnosis stands: polls fail on
//     stale L1 (r8), one-shot first-touch reads always work (r9/r10). The
//     correct primitive is an L1-ONLY invalidate: buffer_inv sc0 (SE scope).
//   Now: LOCAL gate = buffer_inv sc0 + sc0 load of the group flag line that
//   sits DIRTY in the shared XCD L2 (producer: plain write-through stores +
//   vmcnt ack + plain flag). Poll round ~0.1us, no fabric. Budget 600 rounds
//   then sticky SYS (=r10); sentinel one-shot -> truth poll; >=8 bad ->
//   TRUTH-only (=r6); non-32/XCD dispatch -> literal r6 fallback.
// ws: xg bf16 [512][1536][64] | truth [depth][64][512] f16 |
//     fast [8][depth][8][512] f16 | prog int[512] | flag_s int[8][32] |
//     flag_l int[8][64] (256B/group, line-isolated)
// ---------------------------------------------------------------------------

typedef unsigned short ushort_t;
typedef short short8      __attribute__((ext_vector_type(8)));
typedef float floatx4     __attribute__((ext_vector_type(4)));
typedef unsigned int uintx4 __attribute__((ext_vector_type(4)));
typedef unsigned short ushort4v __attribute__((ext_vector_type(4)));
typedef _Float16 half8    __attribute__((ext_vector_type(8)));

#define SEQL 512
#define BATCH 64
#define EMBD 256
#define HID 512
#define G3 1536
#define NOUT 5
#define NGRP 8                     // one group per XCD (fast mode)
#define GRPB 8                     // batches per group (fast mode)
#define GSLOT 8192                 // fast ring slot: 8 x 512 x 2B
#define TSLOT 65536                // truth ring slot: 64 x 512 x 2B
#define RING2 131072               // truth + fast bytes per depth unit
#define XG_BYTES 100663296
#define PROGN 512                  // legacy prog area (includes regs at 384)
#define FLAGN 256                  // flag_s[8][32]
#define FLAG2N 512                 // flag_l[8][64] (padded to 256B/group)
#define ZERON (PROGN + FLAGN + FLAG2N)
#define BAD_LIMIT 8
#define POLL_BUDGET 600

__device__ __forceinline__ float bf2f(ushort_t v){
  union { unsigned u; float f; } x; x.u = ((unsigned)v) << 16; return x.f;
}
__device__ __forceinline__ ushort_t f2bf(float f){
  unsigned u = __float_as_uint(f);
  return (ushort_t)((u + 0x7FFFu + ((u >> 16) & 1u)) >> 16);
}
__device__ __forceinline__ float sigm(float x){
  x = fminf(fmaxf(x, -20.f), 20.f);
  return 1.f / (1.f + __expf(-x));
}
__device__ __forceinline__ float tanh_c(float x){
  x = fminf(fmaxf(x, -10.f), 10.f);
  float e = __expf(2.f * x);
  return (e - 1.f) / (e + 1.f);
}
__device__ __forceinline__ bool has_sent(half8 v){
  union { half8 h; unsigned u[4]; } x; x.h = v;
  bool b = false;
  #pragma unroll
  for (int i = 0; i < 4; ++i){
    b |= ((x.u[i] & 0xFFFFu) == 0xFFFFu);
    b |= ((x.u[i] >> 16) == 0xFFFFu);
  }
  return b;
}

// --- K0: sentinel-fill both rings at SYSTEM scope; zero prog+flags. ---
__global__ __launch_bounds__(256) void gru_init(char* __restrict__ rings,
                                                int* __restrict__ prog){
  size_t i = ((size_t)blockIdx.x * 256 + threadIdx.x) * 16;
  uintx4 s = {0xFFFFFFFFu, 0xFFFFFFFFu, 0xFFFFFFFFu, 0xFFFFFFFFu};
  const char* p = rings + i;
  asm volatile("global_store_dwordx4 %0, %1, off sc0 sc1" :: "v"(p), "v"(s) : "memory");
  if (blockIdx.x == 0){
    int z = 0;
    for (int k = threadIdx.x; k < ZERON; k += 256){
      asm volatile("global_store_dword %0, %1, off sc0 sc1"
                   :: "v"(prog + k), "v"(z) : "memory");
    }
  }
}

// --- K1: x_gates = emb[seq] @ w_ih^T + b_ih, bf16, layout [s][1536][64] ---
#define LDSIDX2(row, chunk) (((row) << 7) + ((((chunk) ^ ((row) & 7))) << 3))
__global__ __launch_bounds__(256) void gru_xgates(
    const int* __restrict__ seq, const float* __restrict__ emb,
    const float* __restrict__ w_ih, const float* __restrict__ b_ih,
    ushort_t* __restrict__ xg)
{
  __shared__ __align__(16) short lA[64 * 128];
  __shared__ __align__(16) short lB[64 * 128];
  const int tid   = threadIdx.x;
  const int sIdx  = blockIdx.x;
  const int nBase = blockIdx.y * 64;
  const int w    = tid >> 6;
  const int l    = tid & 63;
  const int l15  = l & 15;
  const int quad = l >> 4;
  floatx4 acc[4] = {};

  #pragma unroll
  for (int kp = 0; kp < 2; ++kp){
    __syncthreads();
    #pragma unroll
    for (int i = 0; i < 4; ++i){
      int lin = i * 256 + tid;
      int row = lin >> 4;
      int kc  = lin & 15;
      int kbase = kp * 128 + kc * 8;
      int token = seq[(sIdx << 6) + row];
      const float* srcA = emb  + (size_t)token * EMBD + kbase;
      const float* srcB = w_ih + (size_t)(nBase + row) * EMBD + kbase;
      floatx4 a0 = *(const floatx4*)(srcA);
      floatx4 a1 = *(const floatx4*)(srcA + 4);
      floatx4 b0 = *(const floatx4*)(srcB);
      floatx4 b1 = *(const floatx4*)(srcB + 4);
      short8 pa, pb;
      #pragma unroll
      for (int j = 0; j < 4; ++j){
        pa[j]     = (short)f2bf(a0[j]);
        pa[j + 4] = (short)f2bf(a1[j]);
        pb[j]     = (short)f2bf(b0[j]);
        pb[j + 4] = (short)f2bf(b1[j]);
      }
      *(short8*)&lA[LDSIDX2(row, kc)] = pa;
      *(short8*)&lB[LDSIDX2(row, kc)] = pb;
    }
    __syncthreads();
    #pragma unroll
    for (int kc = 0; kc < 4; ++kc){
      int chunk = kc * 4 + quad;
      short8 a = *(const short8*)&lA[LDSIDX2(w * 16 + l15, chunk)];
      #pragma unroll
      for (int s = 0; s < 4; ++s){
        short8 bf = *(const short8*)&lB[LDSIDX2(s * 16 + l15, chunk)];
        acc[s] = __builtin_amdgcn_mfma_f32_16x16x32_bf16(a, bf, acc[s], 0, 0, 0);
      }
    }
  }
  #pragma unroll
  for (int s = 0; s < 4; ++s){
    int g = nBase + s * 16 + l15;
    float bias = b_ih[g];
    ushort4v pk;
    #pragma unroll
    for (int r = 0; r < 4; ++r) pk[r] = f2bf(acc[s][r] + bias);
    *(ushort4v*)(xg + ((size_t)sIdx * G3 + g) * BATCH + (w * 16 + quad * 4)) = pk;
  }
}

// --- K2: recurrence. 256 blocks x 256 threads. ---
__global__ __launch_bounds__(256, 1) void gru_rec(
    const ushort_t* __restrict__ xg, const float* __restrict__ whh,
    const float* __restrict__ bhh, const int* __restrict__ lengths,
    char* __restrict__ truth, char* __restrict__ fastr,
    int* __restrict__ prog, int depth)
{
  __shared__ __align__(16) _Float16 wlds[48 * 64 * 8];   // 49,152 B (B-frags)
  __shared__ __align__(16) _Float16 hscr[4 * 256];       //  2,048 B (repack)
  __shared__ int s_grp, s_slc, s_fast;
  const int tid  = threadIdx.x;
  const int w    = tid >> 6;
  const int l    = tid & 63;
  const int l15  = l & 15;
  const int quad = l >> 4;
  int* flags_s = prog + PROGN;           // [NGRP][32] system-scope flags
  int* flags_l = prog + PROGN + FLAGN;   // [NGRP][64] XCD-local flags

  // ---- rendezvous + XCD-affinity group formation ----
  int* regs = prog + 384;              // [0]=gcount, [1..8]=per-XCD counts
  if (tid == 0){
    unsigned xcd;
    asm volatile("s_getreg_b32 %0, hwreg(HW_REG_XCC_ID)" : "=s"(xcd));
    xcd &= 7u;
    int myx = atomicAdd(&regs[1 + xcd], 1);
    asm volatile("s_waitcnt vmcnt(0)" ::: "memory");  // xcd count visible first
    int gt = atomicAdd(&regs[0], 1);
    int v;
    do {
      asm volatile("s_sleep 1" ::: "memory");
      asm volatile("global_load_dword %0, %1, off sc0 sc1\n\t"
                   "s_waitcnt vmcnt(0)"
                   : "=v"(v) : "v"(&regs[0]) : "memory");
    } while (v < 256);
    int ok = 1;
    #pragma unroll
    for (int x = 0; x < 8; ++x){
      int c;
      asm volatile("global_load_dword %0, %1, off sc0 sc1\n\t"
                   "s_waitcnt vmcnt(0)"
                   : "=v"(c) : "v"(&regs[1 + x]) : "memory");
      ok &= (c == 32);
    }
    s_fast = ok;
    s_grp  = ok ? (int)xcd : 0;
    s_slc  = ok ? (myx & 31) : gt;
  }
  __syncthreads();
  const int fast = s_fast;
  const int grp  = s_grp;
  const int g0   = s_slc;
  if (!fast && g0 >= 32) return;       // fallback: only 32 blocks participate
  const int g = g0 & 31;               // hidden slice [g*16, g*16+16)
  const int j = g * 16 + l15;          // this lane's hidden unit

  // ---- setup: 48 W_hh rows f32->f16 into B-frag LDS (all 4 waves) ----
  #pragma unroll
  for (int i = 0; i < 12; ++i){
    int p  = i * 4 + w;                 // 0..47
    int G  = p >> 4;                    // gate (0=r,1=z,2=n)
    int ks = p & 15;                    // K-step
    const float* src = whh + (size_t)(G * HID + j) * HID + ks * 32 + quad * 8;
    floatx4 f0 = *(const floatx4*)(src);
    floatx4 f1 = *(const floatx4*)(src + 4);
    half8 hv;
    #pragma unroll
    for (int q = 0; q < 4; ++q){ hv[q] = (_Float16)f0[q]; hv[q + 4] = (_Float16)f1[q]; }
    *(half8*)&wlds[((size_t)p * 64 + l) * 8] = hv;
  }
  __syncthreads();
  if (fast && tid >= 64) return;       // fast mode: wave 0 runs alone

  char* fastb = fastr + (size_t)grp * depth * GSLOT;
  const int locb = fast ? ((quad & 1) * 4) : (quad * 4);  // wave-local batch base
  const int gb   = fast ? (grp * GRPB + locb) : (w * 16 + locb);  // global batch
  const int arow = l15 & 7;                                // fast ring A-row
  const int trow = fast ? (grp * GRPB + (l15 & 7)) : (w * 16 + l15); // truth row
  const float bhR = bhh[j], bhZ = bhh[HID + j], bhN = bhh[2 * HID + j];
  int   len[4];
  float h[4];
  #pragma unroll
  for (int r = 0; r < 4; ++r){ len[r] = lengths[gb + r]; h[r] = 0.f; }
  const int Lmax  = lengths[0];        // global max: all blocks run to Lmax
  const int mask  = depth - 1;
  const bool reuse = (depth < Lmax);
  const int flagmode = fast && !reuse; // flag-released L2 exchange
  const int* fpoll_s = flags_s + grp * 32 + (l & 31);
  int* fpub_s = flags_s + grp * 32 + g;
  const int* fpoll_l = flags_l + grp * 64 + (l & 31);
  int* fpub_l = flags_l + grp * 64 + g;
  int cmin = 0;
  int badcnt = 0;
  // mode: 2 = LOCAL gate (L1-inv+L2), 1 = SYS gate (sc0sc1), 0 = TRUTH only
  int mode = flagmode ? 2 : 0;

  for (int t = 0; t < Lmax; ++t){
    // 0) ring-reuse guard (legacy modes only; dead when depth >= Lmax)
    if (reuse && t >= depth){
      int target = t - depth + 2;
      if (cmin < target){
        int tgt2 = target + 4;
        if (fast){
          const int* pp = prog + 128 + grp * 32 + (l & 31);
          while (true){
            int p0;
            asm volatile("global_load_dword %0, %1, off sc0 sc1\n\t"
                         "s_waitcnt vmcnt(0)"
                         : "=v"(p0) : "v"(pp) : "memory");
            if (__all(p0 >= tgt2)) break;
            __builtin_amdgcn_s_sleep(2);
          }
        } else {
          while (true){
            int p0, p1;
            asm volatile("global_load_dword %0, %2, off sc0 sc1\n\t"
                         "global_load_dword %1, %3, off sc0 sc1\n\t"
                         "s_waitcnt vmcnt(0)"
                         : "=v"(p0), "=v"(p1) : "v"(prog + l), "v"(prog + 64 + l)
                         : "memory");
            if (__all(p0 >= tgt2 && p1 >= tgt2)) break;
            __builtin_amdgcn_s_sleep(2);
          }
        }
        cmin = tgt2;
      }
    }

    // 1) xg prefetch (independent of h)
    const ushort_t* xt = xg + (size_t)t * G3 * BATCH;
    ushort4v xR = __builtin_nontemporal_load(
        (const ushort4v*)(xt + (size_t)(          j) * BATCH + gb));
    ushort4v xZ = __builtin_nontemporal_load(
        (const ushort4v*)(xt + (size_t)(HID     + j) * BATCH + gb));
    ushort4v xN = __builtin_nontemporal_load(
        (const ushort4v*)(xt + (size_t)(2 * HID + j) * BATCH + gb));

    // 2) consume h(t-1)
    floatx4 aR = {0.f,0.f,0.f,0.f}, aZ = {0.f,0.f,0.f,0.f}, aN = {0.f,0.f,0.f,0.f};
    if (t > 0){
      const int slotp = (t - 1) & mask;
      const char* rowf = fastb + (size_t)slotp * GSLOT
                       + (size_t)arow * 1024 + quad * 16;
      const char* rowt = truth + (size_t)slotp * TSLOT
                       + (size_t)trow * 1024 + quad * 16;
      half8 aF[16];
      bool have = false;
      if (mode == 2){
        // 2a-LOCAL: L1-ONLY invalidate (buffer_inv sc0, SE scope) -> sc0
        //     load reads the dirty flag line in the SHARED XCD L2. The L2 is
        //     NOT touched (r11's agent fence emitted buffer_inv sc1 and
        //     flushed L2 too -> fabric RTs; this is the corrected primitive).
        int miss = 0;
        while (true){
          asm volatile("buffer_inv sc0" ::: "memory");
          int fv;
          asm volatile("global_load_dword %0, %1, off sc0\n\t"
                       "s_waitcnt vmcnt(0)"
                       : "=v"(fv) : "v"(fpoll_l) : "memory");
          if (__all(fv >= t)) break;
          if (++miss > POLL_BUDGET){ mode = 1; break; }  // sticky downgrade
          if (miss > 32) __builtin_amdgcn_s_sleep(2);
        }
      }
      if (mode == 1){
        // 2a-SYS: r10-proven system-scope flag gate
        int miss = 0;
        while (true){
          int fv;
          asm volatile("global_load_dword %0, %1, off sc0 sc1\n\t"
                       "s_waitcnt vmcnt(0)"
                       : "=v"(fv) : "v"(fpoll_s) : "memory");
          if (__all(fv >= t)) break;
          ++miss;
          if (miss > 64) __builtin_amdgcn_s_sleep(8);
          else           __builtin_amdgcn_s_sleep(1);
        }
      }
      if (mode >= 1){
        // 2b: one-shot data read from the shared XCD L2 (first touch of this
        //     address by this block; L1 freshly invalidated in LOCAL)
        #pragma unroll
        for (int ks = 0; ks < 16; ++ks){
          const char* pa = rowf + ks * 64;
          asm volatile("global_load_dwordx4 %0, %1, off sc0"
                       : "=v"(aF[ks]) : "v"(pa) : "memory");
        }
        asm volatile("s_waitcnt vmcnt(0)"
                     : "+v"(aF[0]),  "+v"(aF[1]),  "+v"(aF[2]),  "+v"(aF[3]),
                       "+v"(aF[4]),  "+v"(aF[5]),  "+v"(aF[6]),  "+v"(aF[7]),
                       "+v"(aF[8]),  "+v"(aF[9]),  "+v"(aF[10]), "+v"(aF[11]),
                       "+v"(aF[12]), "+v"(aF[13]), "+v"(aF[14]), "+v"(aF[15])
                     :: "memory");
        bool bad = false;
        #pragma unroll
        for (int ks = 0; ks < 16; ++ks) bad |= has_sent(aF[ks]);
        have = !__any(bad);
        if (!have && ++badcnt >= BAD_LIMIT) mode = 0;
      }
      if (!have){
        // legacy / escalation: self-synchronizing sentinel poll on truth
        int rounds = 0;
        while (true){
          if (rounds){
            if (rounds > 64) __builtin_amdgcn_s_sleep(8);
            else             __builtin_amdgcn_s_sleep(2);
          }
          ++rounds;
          #pragma unroll
          for (int ks = 0; ks < 16; ++ks){
            const char* pa = rowt + ks * 64;
            asm volatile("global_load_dwordx4 %0, %1, off sc0 sc1"
                         : "=v"(aF[ks]) : "v"(pa) : "memory");
          }
          asm volatile("s_waitcnt vmcnt(0)"
                       : "+v"(aF[0]),  "+v"(aF[1]),  "+v"(aF[2]),  "+v"(aF[3]),
                         "+v"(aF[4]),  "+v"(aF[5]),  "+v"(aF[6]),  "+v"(aF[7]),
                         "+v"(aF[8]),  "+v"(aF[9]),  "+v"(aF[10]), "+v"(aF[11]),
                         "+v"(aF[12]), "+v"(aF[13]), "+v"(aF[14]), "+v"(aF[15])
                       :: "memory");
          bool bad = false;
          #pragma unroll
          for (int ks = 0; ks < 16; ++ks) bad |= has_sent(aF[ks]);
          if (!__any(bad)) break;
        }
      }
      #pragma unroll
      for (int ks = 0; ks < 16; ++ks){
        half8 a  = aF[ks];
        half8 b0 = *(const half8*)&wlds[((size_t)(0 * 16 + ks) * 64 + l) * 8];
        half8 b1 = *(const half8*)&wlds[((size_t)(1 * 16 + ks) * 64 + l) * 8];
        half8 b2 = *(const half8*)&wlds[((size_t)(2 * 16 + ks) * 64 + l) * 8];
        aR = __builtin_amdgcn_mfma_f32_16x16x32_f16(a, b0, aR, 0, 0, 0);
        aZ = __builtin_amdgcn_mfma_f32_16x16x32_f16(a, b1, aZ, 0, 0, 0);
        aN = __builtin_amdgcn_mfma_f32_16x16x32_f16(a, b2, aN, 0, 0, 0);
      }
      // restore sentinels on consumed truth chunks (legacy reuse only)
      if (reuse){
        uintx4 sv = {0xFFFFFFFFu, 0xFFFFFFFFu, 0xFFFFFFFFu, 0xFFFFFFFFu};
        if (!fast || l15 < 8){
          #pragma unroll
          for (int ks = 0; ks < 16; ++ks){
            const char* pt = rowt + ks * 64;
            asm volatile("global_store_dwordx4 %0, %1, off sc0 sc1"
                         :: "v"(pt), "v"(sv) : "memory");
          }
        }
      }
    }

    // 3) gates + h update (f32 carry); mirrored quads duplicate harmlessly
    #pragma unroll
    for (int r = 0; r < 4; ++r){
      float rr = sigm(bf2f(xR[r]) + aR[r] + bhR);
      float zz = sigm(bf2f(xZ[r]) + aZ[r] + bhZ);
      float nn = tanh_c(bf2f(xN[r]) + rr * (aN[r] + bhN));
      float hn = (1.f - zz) * nn + zz * h[r];
      h[r] = (t < len[r]) ? hn : h[r];
    }

    // 4) intra-wave repack via LDS, then publish h(t)
    _Float16* scr = hscr + w * 256;
    if (!fast || quad < 2){
      #pragma unroll
      for (int r = 0; r < 4; ++r) scr[(locb + r) * 16 + l15] = (_Float16)h[r];
    }
    asm volatile("s_waitcnt lgkmcnt(0)" ::: "memory");   // wave-local DS order
    if (flagmode){
      // release: PLAIN fast-data stores (write-through into own XCD L2) ->
      // vmcnt ack -> PLAIN local flag -> sc0sc1 system flag -> sc0sc1 truth
      if (l < 16){
        int bl = l >> 1;
        int hc = l & 1;
        half8 ch = *(const half8*)&scr[bl * 16 + hc * 8];
        const char* df = fastb + (size_t)(t & mask) * GSLOT
                       + (size_t)bl * 1024 + (size_t)g * 32 + (size_t)hc * 16;
        asm volatile("global_store_dwordx4 %0, %1, off"
                     :: "v"(df), "v"(ch) : "memory");
      }
      asm volatile("s_waitcnt vmcnt(0)" ::: "memory");   // data in XCD L2
      if (l == 0){
        int pv = t + 1;
        asm volatile("global_store_dword %0, %1, off"
                     :: "v"(fpub_l), "v"(pv) : "memory");
        asm volatile("global_store_dword %0, %1, off sc0 sc1"
                     :: "v"(fpub_s), "v"(pv) : "memory");
      }
      if (l < 16){
        int bl = l >> 1;
        int hc = l & 1;
        half8 ch = *(const half8*)&scr[bl * 16 + hc * 8];
        const char* dt = truth + (size_t)(t & mask) * TSLOT
                       + (size_t)(grp * GRPB + bl) * 1024
                       + (size_t)g * 32 + (size_t)hc * 16;
        asm volatile("global_store_dwordx4 %0, %1, off sc0 sc1"
                     :: "v"(dt), "v"(ch) : "memory");
      }
    } else {
      const int pubN = fast ? 16 : 32;
      if (l < pubN){
        int bl = l >> 1;
        int hc = l & 1;
        half8 ch = *(const half8*)&scr[bl * 16 + hc * 8];
        int gbatch = fast ? (grp * GRPB + bl) : (w * 16 + bl);
        const char* dt = truth + (size_t)(t & mask) * TSLOT
                       + (size_t)gbatch * 1024 + (size_t)g * 32 + (size_t)hc * 16;
        asm volatile("global_store_dwordx4 %0, %1, off sc0 sc1"
                     :: "v"(dt), "v"(ch) : "memory");
      }
      // 5) coarse progress publish (reuse mode only), ordered after restores
      if (reuse && ((t & 7) == 7)){
        asm volatile("s_waitcnt vmcnt(0)" ::: "memory");
        if (l == 0){
          int pv = t + 1;
          const int* pp = fast ? (prog + 128 + grp * 32 + g) : (prog + w * 32 + g);
          asm volatile("global_store_dword %0, %1, off sc0 sc1"
                       :: "v"(pp), "v"(pv) : "memory");
        }
      }
    }
  }
}

// --- K3: logits + log_softmax from truth slot (Lmax-1). 64 blocks x 64. ---
__global__ __launch_bounds__(64) void gru_out(
    const char* __restrict__ truth, const int* __restrict__ lengths,
    const float* __restrict__ wout, const float* __restrict__ bout,
    float* __restrict__ out, int depth)
{
  const int b = blockIdx.x, l = threadIdx.x;
  const int Lmax = lengths[0];
  const _Float16* h = (const _Float16*)(truth
      + (size_t)((Lmax - 1) & (depth - 1)) * TSLOT + (size_t)b * 1024);
  half8 hv = *(const half8*)(h + l * 8);
  float p[NOUT];
  #pragma unroll
  for (int o = 0; o < NOUT; ++o){
    const float* wr = wout + o * HID + l * 8;
    float a = 0.f;
    #pragma unroll
    for (int i = 0; i < 8; ++i) a += wr[i] * (float)hv[i];
    #pragma unroll
    for (int d = 32; d >= 1; d >>= 1) a += __shfl_down(a, d, 64);
    p[o] = a;
  }
  if (l == 0){
    float lg[NOUT], m = -1e30f;
    #pragma unroll
    for (int o = 0; o < NOUT; ++o){
      float v = p[o] + bout[o];
      if (!(v == v)) v = -1.0f;
      lg[o] = v; m = fmaxf(m, v);
    }
    float ssum = 0.f;
    #pragma unroll
    for (int o = 0; o < NOUT; ++o) ssum += __expf(lg[o] - m);
    float ls = __logf(ssum);
    #pragma unroll
    for (int o = 0; o < NOUT; ++o) out[b * NOUT + o] = lg[o] - m - ls;
  }
}

extern "C" void kernel_launch(void* const* d_in, const int* in_sizes, int n_in,
                              void* d_out, int out_size, void* d_ws, size_t ws_size,
                              hipStream_t stream) {
  (void)in_sizes; (void)n_in; (void)out_size;
  const int*   seq     = (const int*)d_in[0];
  const int*   lengths = (const int*)d_in[1];
  const float* emb     = (const float*)d_in[2];
  const float* w_ih    = (const float*)d_in[3];
  const float* w_hh    = (const float*)d_in[4];
  const float* b_ih    = (const float*)d_in[5];
  const float* b_hh    = (const float*)d_in[6];
  const float* w_out   = (const float*)d_in[7];
  const float* b_out   = (const float*)d_in[8];
  float*       outp    = (float*)d_out;

  // ring depth: largest power of two in [16, 512] such that both rings
  // (depth * 128 KiB) + prog/flags fit the workspace after xg.
  size_t avail = (ws_size > (size_t)XG_BYTES + 32768)
               ? ws_size - (size_t)XG_BYTES - 32768 : 0;
  int depth = 16;
  while (depth < 512 && ((size_t)(depth << 1) * RING2) <= avail) depth <<= 1;

  char* ws = (char*)d_ws;
  ushort_t* xg    = (ushort_t*)ws;                                 // 100,663,296 B
  char*     truth = ws + XG_BYTES;                                 // depth*65,536 B
  char*     fastr = truth + (size_t)depth * TSLOT;                 // depth*65,536 B
  int*      prog  = (int*)(fastr + (size_t)depth * TSLOT);         // 1280 ints

  gru_init<<<depth * 32, 256, 0, stream>>>(truth, prog);
  dim3 g1(SEQL, G3 / 64);
  gru_xgates<<<g1, 256, 0, stream>>>(seq, emb, w_ih, b_ih, xg);
  gru_rec<<<256, 256, 0, stream>>>(xg, w_hh, b_hh, lengths, truth, fastr, prog, depth);
  gru_out<<<BATCH, 64, 0, stream>>>(truth, lengths, w_out, b_out, outp, depth);
}

// Round 8
// 2200.035 us; speedup vs baseline: 1.2577x; 1.0213x over previous
//
#include <hip/hip_runtime.h>

// ---------------------------------------------------------------------------
// SimpleGRU on MI355X (gfx950). Round 13: L2-local atomic-counter release.
//   r10 (rec 3.88us/step): system-scope flag gate -> fabric RT floor.
//   r12 (rec 4.10us/step): plain-store + buffer_inv sc0 LOCAL path never hit:
//     either plain stores lingered in producer L1 (write-back; r9's working
//     one-shots were of sc0-stored data) or buffer_inv sc0 didn't invalidate
//     the polling L1. Fix kills both: the exchange uses primitives that
//     CANNOT touch L1. Atomics execute at the issuing XCD's L2 unless sc1
//     (that's why cross-XCD atomics need device scope) and are never L1-
//     cached. Producer: 16 sc0 data stores -> vmcnt(0) (acked at L2) -> ONE
//     non-sc1 global_atomic_add ctr[grp][slot] (L2 atomic unit, ~0.1us for
//     all 32, vs 1-3us when r9 did this at the fabric). Consumer: lane 0
//     polls atomic_add(ptr,0) sc0 (returns old, executes at L2, no L1),
//     shfl-broadcast, gate at ==32, then proven one-shot sc0 data read.
//   Ladder (all proven): budget 400 -> sticky SYS (=r10); sentinel one-shot
//   -> truth poll; >=8 bad -> TRUTH-only (=r6); non-32/XCD -> literal r6.
// ws: xg bf16 [512][1536][64] | truth [depth][64][512] f16 |
//     fast [8][depth][8][512] f16 | prog int[1280] | ctr int[8][512][16]
// ---------------------------------------------------------------------------

typedef unsigned short ushort_t;
typedef short short8      __attribute__((ext_vector_type(8)));
typedef float floatx4     __attribute__((ext_vector_type(4)));
typedef unsigned int uintx4 __attribute__((ext_vector_type(4)));
typedef unsigned short ushort4v __attribute__((ext_vector_type(4)));
typedef _Float16 half8    __attribute__((ext_vector_type(8)));

#define SEQL 512
#define BATCH 64
#define EMBD 256
#define HID 512
#define G3 1536
#define NOUT 5
#define NGRP 8                     // one group per XCD (fast mode)
#define GRPB 8                     // batches per group (fast mode)
#define GSLOT 8192                 // fast ring slot: 8 x 512 x 2B
#define TSLOT 65536                // truth ring slot: 64 x 512 x 2B
#define RING2 131072               // truth + fast bytes per depth unit
#define XG_BYTES 100663296
#define PROGN 512                  // legacy prog area (includes regs at 384)
#define FLAGN 256                  // flag_s[8][32]
#define FLAG2N 512                 // (legacy local flags, zeroed, unused)
#define CTRO (PROGN + FLAGN + FLAG2N)   // 1280: ctr area, 64B-padded slots
#define CTRN (NGRP * 512 * 16)          // 65536 ints
#define ZERON (CTRO + CTRN)             // 66816 ints zeroed by init
#define BAD_LIMIT 8
#define POLL_BUDGET 400

__device__ __forceinline__ float bf2f(ushort_t v){
  union { unsigned u; float f; } x; x.u = ((unsigned)v) << 16; return x.f;
}
__device__ __forceinline__ ushort_t f2bf(float f){
  unsigned u = __float_as_uint(f);
  return (ushort_t)((u + 0x7FFFu + ((u >> 16) & 1u)) >> 16);
}
__device__ __forceinline__ float sigm(float x){
  x = fminf(fmaxf(x, -20.f), 20.f);
  return 1.f / (1.f + __expf(-x));
}
__device__ __forceinline__ float tanh_c(float x){
  x = fminf(fmaxf(x, -10.f), 10.f);
  float e = __expf(2.f * x);
  return (e - 1.f) / (e + 1.f);
}
__device__ __forceinline__ bool has_sent(half8 v){
  union { half8 h; unsigned u[4]; } x; x.h = v;
  bool b = false;
  #pragma unroll
  for (int i = 0; i < 4; ++i){
    b |= ((x.u[i] & 0xFFFFu) == 0xFFFFu);
    b |= ((x.u[i] >> 16) == 0xFFFFu);
  }
  return b;
}

// --- K0: sentinel-fill both rings at SYSTEM scope; zero prog+flags+ctrs. ---
__global__ __launch_bounds__(256) void gru_init(char* __restrict__ rings,
                                                int* __restrict__ prog){
  size_t i = ((size_t)blockIdx.x * 256 + threadIdx.x) * 16;
  uintx4 s = {0xFFFFFFFFu, 0xFFFFFFFFu, 0xFFFFFFFFu, 0xFFFFFFFFu};
  const char* p = rings + i;
  asm volatile("global_store_dwordx4 %0, %1, off sc0 sc1" :: "v"(p), "v"(s) : "memory");
  int k = blockIdx.x * 256 + threadIdx.x;       // 261 blocks cover ZERON exactly
  if (k < ZERON){
    int z = 0;
    asm volatile("global_store_dword %0, %1, off sc0 sc1"
                 :: "v"(prog + k), "v"(z) : "memory");
  }
}

// --- K1: x_gates = emb[seq] @ w_ih^T + b_ih, bf16, layout [s][1536][64] ---
#define LDSIDX2(row, chunk) (((row) << 7) + ((((chunk) ^ ((row) & 7))) << 3))
__global__ __launch_bounds__(256) void gru_xgates(
    const int* __restrict__ seq, const float* __restrict__ emb,
    const float* __restrict__ w_ih, const float* __restrict__ b_ih,
    ushort_t* __restrict__ xg)
{
  __shared__ __align__(16) short lA[64 * 128];
  __shared__ __align__(16) short lB[64 * 128];
  const int tid   = threadIdx.x;
  const int sIdx  = blockIdx.x;
  const int nBase = blockIdx.y * 64;
  const int w    = tid >> 6;
  const int l    = tid & 63;
  const int l15  = l & 15;
  const int quad = l >> 4;
  floatx4 acc[4] = {};

  #pragma unroll
  for (int kp = 0; kp < 2; ++kp){
    __syncthreads();
    #pragma unroll
    for (int i = 0; i < 4; ++i){
      int lin = i * 256 + tid;
      int row = lin >> 4;
      int kc  = lin & 15;
      int kbase = kp * 128 + kc * 8;
      int token = seq[(sIdx << 6) + row];
      const float* srcA = emb  + (size_t)token * EMBD + kbase;
      const float* srcB = w_ih + (size_t)(nBase + row) * EMBD + kbase;
      floatx4 a0 = *(const floatx4*)(srcA);
      floatx4 a1 = *(const floatx4*)(srcA + 4);
      floatx4 b0 = *(const floatx4*)(srcB);
      floatx4 b1 = *(const floatx4*)(srcB + 4);
      short8 pa, pb;
      #pragma unroll
      for (int j = 0; j < 4; ++j){
        pa[j]     = (short)f2bf(a0[j]);
        pa[j + 4] = (short)f2bf(a1[j]);
        pb[j]     = (short)f2bf(b0[j]);
        pb[j + 4] = (short)f2bf(b1[j]);
      }
      *(short8*)&lA[LDSIDX2(row, kc)] = pa;
      *(short8*)&lB[LDSIDX2(row, kc)] = pb;
    }
    __syncthreads();
    #pragma unroll
    for (int kc = 0; kc < 4; ++kc){
      int chunk = kc * 4 + quad;
      short8 a = *(const short8*)&lA[LDSIDX2(w * 16 + l15, chunk)];
      #pragma unroll
      for (int s = 0; s < 4; ++s){
        short8 bf = *(const short8*)&lB[LDSIDX2(s * 16 + l15, chunk)];
        acc[s] = __builtin_amdgcn_mfma_f32_16x16x32_bf16(a, bf, acc[s], 0, 0, 0);
      }
    }
  }
  #pragma unroll
  for (int s = 0; s < 4; ++s){
    int g = nBase + s * 16 + l15;
    float bias = b_ih[g];
    ushort4v pk;
    #pragma unroll
    for (int r = 0; r < 4; ++r) pk[r] = f2bf(acc[s][r] + bias);
    *(ushort4v*)(xg + ((size_t)sIdx * G3 + g) * BATCH + (w * 16 + quad * 4)) = pk;
  }
}

// --- K2: recurrence. 256 blocks x 256 threads. ---
__global__ __launch_bounds__(256, 1) void gru_rec(
    const ushort_t* __restrict__ xg, const float* __restrict__ whh,
    const float* __restrict__ bhh, const int* __restrict__ lengths,
    char* __restrict__ truth, char* __restrict__ fastr,
    int* __restrict__ prog, int depth)
{
  __shared__ __align__(16) _Float16 wlds[48 * 64 * 8];   // 49,152 B (B-frags)
  __shared__ __align__(16) _Float16 hscr[4 * 256];       //  2,048 B (repack)
  __shared__ int s_grp, s_slc, s_fast;
  const int tid  = threadIdx.x;
  const int w    = tid >> 6;
  const int l    = tid & 63;
  const int l15  = l & 15;
  const int quad = l >> 4;
  int* flags_s = prog + PROGN;           // [NGRP][32] system-scope flags
  int* ctr_l   = prog + CTRO;            // [NGRP][512][16] L2-local counters

  // ---- rendezvous + XCD-affinity group formation ----
  int* regs = prog + 384;              // [0]=gcount, [1..8]=per-XCD counts
  if (tid == 0){
    unsigned xcd;
    asm volatile("s_getreg_b32 %0, hwreg(HW_REG_XCC_ID)" : "=s"(xcd));
    xcd &= 7u;
    int myx = atomicAdd(&regs[1 + xcd], 1);
    asm volatile("s_waitcnt vmcnt(0)" ::: "memory");  // xcd count visible first
    int gt = atomicAdd(&regs[0], 1);
    int v;
    do {
      asm volatile("s_sleep 1" ::: "memory");
      asm volatile("global_load_dword %0, %1, off sc0 sc1\n\t"
                   "s_waitcnt vmcnt(0)"
                   : "=v"(v) : "v"(&regs[0]) : "memory");
    } while (v < 256);
    int ok = 1;
    #pragma unroll
    for (int x = 0; x < 8; ++x){
      int c;
      asm volatile("global_load_dword %0, %1, off sc0 sc1\n\t"
                   "s_waitcnt vmcnt(0)"
                   : "=v"(c) : "v"(&regs[1 + x]) : "memory");
      ok &= (c == 32);
    }
    s_fast = ok;
    s_grp  = ok ? (int)xcd : 0;
    s_slc  = ok ? (myx & 31) : gt;
  }
  __syncthreads();
  const int fast = s_fast;
  const int grp  = s_grp;
  const int g0   = s_slc;
  if (!fast && g0 >= 32) return;       // fallback: only 32 blocks participate
  const int g = g0 & 31;               // hidden slice [g*16, g*16+16)
  const int j = g * 16 + l15;          // this lane's hidden unit

  // ---- setup: 48 W_hh rows f32->f16 into B-frag LDS (all 4 waves) ----
  #pragma unroll
  for (int i = 0; i < 12; ++i){
    int p  = i * 4 + w;                 // 0..47
    int G  = p >> 4;                    // gate (0=r,1=z,2=n)
    int ks = p & 15;                    // K-step
    const float* src = whh + (size_t)(G * HID + j) * HID + ks * 32 + quad * 8;
    floatx4 f0 = *(const floatx4*)(src);
    floatx4 f1 = *(const floatx4*)(src + 4);
    half8 hv;
    #pragma unroll
    for (int q = 0; q < 4; ++q){ hv[q] = (_Float16)f0[q]; hv[q + 4] = (_Float16)f1[q]; }
    *(half8*)&wlds[((size_t)p * 64 + l) * 8] = hv;
  }
  __syncthreads();
  if (fast && tid >= 64) return;       // fast mode: wave 0 runs alone

  char* fastb = fastr + (size_t)grp * depth * GSLOT;
  const int locb = fast ? ((quad & 1) * 4) : (quad * 4);  // wave-local batch base
  const int gb   = fast ? (grp * GRPB + locb) : (w * 16 + locb);  // global batch
  const int arow = l15 & 7;                                // fast ring A-row
  const int trow = fast ? (grp * GRPB + (l15 & 7)) : (w * 16 + l15); // truth row
  const float bhR = bhh[j], bhZ = bhh[HID + j], bhN = bhh[2 * HID + j];
  int   len[4];
  float h[4];
  #pragma unroll
  for (int r = 0; r < 4; ++r){ len[r] = lengths[gb + r]; h[r] = 0.f; }
  const int Lmax  = lengths[0];        // global max: all blocks run to Lmax
  const int mask  = depth - 1;
  const bool reuse = (depth < Lmax);
  const int flagmode = fast && !reuse; // counter-released L2 exchange
  const int* fpoll_s = flags_s + grp * 32 + (l & 31);
  int* fpub_s = flags_s + grp * 32 + g;
  int cmin = 0;
  int badcnt = 0;
  // mode: 2 = LOCAL gate (L2 atomic ctr), 1 = SYS gate (sc0sc1), 0 = TRUTH
  int mode = flagmode ? 2 : 0;

  for (int t = 0; t < Lmax; ++t){
    // 0) ring-reuse guard (legacy modes only; dead when depth >= Lmax)
    if (reuse && t >= depth){
      int target = t - depth + 2;
      if (cmin < target){
        int tgt2 = target + 4;
        if (fast){
          const int* pp = prog + 128 + grp * 32 + (l & 31);
          while (true){
            int p0;
            asm volatile("global_load_dword %0, %1, off sc0 sc1\n\t"
                         "s_waitcnt vmcnt(0)"
                         : "=v"(p0) : "v"(pp) : "memory");
            if (__all(p0 >= tgt2)) break;
            __builtin_amdgcn_s_sleep(2);
          }
        } else {
          while (true){
            int p0, p1;
            asm volatile("global_load_dword %0, %2, off sc0 sc1\n\t"
                         "global_load_dword %1, %3, off sc0 sc1\n\t"
                         "s_waitcnt vmcnt(0)"
                         : "=v"(p0), "=v"(p1) : "v"(prog + l), "v"(prog + 64 + l)
                         : "memory");
            if (__all(p0 >= tgt2 && p1 >= tgt2)) break;
            __builtin_amdgcn_s_sleep(2);
          }
        }
        cmin = tgt2;
      }
    }

    // 1) xg prefetch (independent of h)
    const ushort_t* xt = xg + (size_t)t * G3 * BATCH;
    ushort4v xR = __builtin_nontemporal_load(
        (const ushort4v*)(xt + (size_t)(          j) * BATCH + gb));
    ushort4v xZ = __builtin_nontemporal_load(
        (const ushort4v*)(xt + (size_t)(HID     + j) * BATCH + gb));
    ushort4v xN = __builtin_nontemporal_load(
        (const ushort4v*)(xt + (size_t)(2 * HID + j) * BATCH + gb));

    // 2) consume h(t-1)
    floatx4 aR = {0.f,0.f,0.f,0.f}, aZ = {0.f,0.f,0.f,0.f}, aN = {0.f,0.f,0.f,0.f};
    if (t > 0){
      const int slotp = (t - 1) & mask;
      const char* rowf = fastb + (size_t)slotp * GSLOT
                       + (size_t)arow * 1024 + quad * 16;
      const char* rowt = truth + (size_t)slotp * TSLOT
                       + (size_t)trow * 1024 + quad * 16;
      half8 aF[16];
      bool have = false;
      if (mode == 2){
        // 2a-LOCAL: lane 0 polls the slot counter with a RETURNING atomic
        //     (no sc1 -> executes at this XCD's L2 atomic unit; atomics are
        //     never served by L1, so staleness is structurally impossible).
        const int* cp = ctr_l + ((grp * 512 + slotp) << 4);
        int miss = 0;
        while (true){
          int cv = 0;
          if (l == 0){
            int zro = 0;
            asm volatile("global_atomic_add %0, %1, %2, off sc0\n\t"
                         "s_waitcnt vmcnt(0)"
                         : "=v"(cv) : "v"(cp), "v"(zro) : "memory");
          }
          cv = __shfl(cv, 0);
          if (cv >= 32) break;
          if (++miss > POLL_BUDGET){ mode = 1; break; }  // sticky downgrade
          if (miss > 32) __builtin_amdgcn_s_sleep(1);
        }
      }
      if (mode == 1){
        // 2a-SYS: r10-proven system-scope flag gate
        int miss = 0;
        while (true){
          int fv;
          asm volatile("global_load_dword %0, %1, off sc0 sc1\n\t"
                       "s_waitcnt vmcnt(0)"
                       : "=v"(fv) : "v"(fpoll_s) : "memory");
          if (__all(fv >= t)) break;
          ++miss;
          if (miss > 64) __builtin_amdgcn_s_sleep(8);
          else           __builtin_amdgcn_s_sleep(1);
        }
      }
      if (mode >= 1){
        // 2b: one-shot sc0 data read (first touch by this block each step)
        #pragma unroll
        for (int ks = 0; ks < 16; ++ks){
          const char* pa = rowf + ks * 64;
          asm volatile("global_load_dwordx4 %0, %1, off sc0"
                       : "=v"(aF[ks]) : "v"(pa) : "memory");
        }
        asm volatile("s_waitcnt vmcnt(0)"
                     : "+v"(aF[0]),  "+v"(aF[1]),  "+v"(aF[2]),  "+v"(aF[3]),
                       "+v"(aF[4]),  "+v"(aF[5]),  "+v"(aF[6]),  "+v"(aF[7]),
                       "+v"(aF[8]),  "+v"(aF[9]),  "+v"(aF[10]), "+v"(aF[11]),
                       "+v"(aF[12]), "+v"(aF[13]), "+v"(aF[14]), "+v"(aF[15])
                     :: "memory");
        bool bad = false;
        #pragma unroll
        for (int ks = 0; ks < 16; ++ks) bad |= has_sent(aF[ks]);
        have = !__any(bad);
        if (!have && ++badcnt >= BAD_LIMIT) mode = 0;
      }
      if (!have){
        // legacy / escalation: self-synchronizing sentinel poll on truth
        int rounds = 0;
        while (true){
          if (rounds){
            if (rounds > 64) __builtin_amdgcn_s_sleep(8);
            else             __builtin_amdgcn_s_sleep(2);
          }
          ++rounds;
          #pragma unroll
          for (int ks = 0; ks < 16; ++ks){
            const char* pa = rowt + ks * 64;
            asm volatile("global_load_dwordx4 %0, %1, off sc0 sc1"
                         : "=v"(aF[ks]) : "v"(pa) : "memory");
          }
          asm volatile("s_waitcnt vmcnt(0)"
                       : "+v"(aF[0]),  "+v"(aF[1]),  "+v"(aF[2]),  "+v"(aF[3]),
                         "+v"(aF[4]),  "+v"(aF[5]),  "+v"(aF[6]),  "+v"(aF[7]),
                         "+v"(aF[8]),  "+v"(aF[9]),  "+v"(aF[10]), "+v"(aF[11]),
                         "+v"(aF[12]), "+v"(aF[13]), "+v"(aF[14]), "+v"(aF[15])
                       :: "memory");
          bool bad = false;
          #pragma unroll
          for (int ks = 0; ks < 16; ++ks) bad |= has_sent(aF[ks]);
          if (!__any(bad)) break;
        }
      }
      #pragma unroll
      for (int ks = 0; ks < 16; ++ks){
        half8 a  = aF[ks];
        half8 b0 = *(const half8*)&wlds[((size_t)(0 * 16 + ks) * 64 + l) * 8];
        half8 b1 = *(const half8*)&wlds[((size_t)(1 * 16 + ks) * 64 + l) * 8];
        half8 b2 = *(const half8*)&wlds[((size_t)(2 * 16 + ks) * 64 + l) * 8];
        aR = __builtin_amdgcn_mfma_f32_16x16x32_f16(a, b0, aR, 0, 0, 0);
        aZ = __builtin_amdgcn_mfma_f32_16x16x32_f16(a, b1, aZ, 0, 0, 0);
        aN = __builtin_amdgcn_mfma_f32_16x16x32_f16(a, b2, aN, 0, 0, 0);
      }
      // restore sentinels on consumed truth chunks (legacy reuse only)
      if (reuse){
        uintx4 sv = {0xFFFFFFFFu, 0xFFFFFFFFu, 0xFFFFFFFFu, 0xFFFFFFFFu};
        if (!fast || l15 < 8){
          #pragma unroll
          for (int ks = 0; ks < 16; ++ks){
            const char* pt = rowt + ks * 64;
            asm volatile("global_store_dwordx4 %0, %1, off sc0 sc1"
                         :: "v"(pt), "v"(sv) : "memory");
          }
        }
      }
    }

    // 3) gates + h update (f32 carry); mirrored quads duplicate harmlessly
    #pragma unroll
    for (int r = 0; r < 4; ++r){
      float rr = sigm(bf2f(xR[r]) + aR[r] + bhR);
      float zz = sigm(bf2f(xZ[r]) + aZ[r] + bhZ);
      float nn = tanh_c(bf2f(xN[r]) + rr * (aN[r] + bhN));
      float hn = (1.f - zz) * nn + zz * h[r];
      h[r] = (t < len[r]) ? hn : h[r];
    }

    // 4) intra-wave repack via LDS, then publish h(t)
    _Float16* scr = hscr + w * 256;
    if (!fast || quad < 2){
      #pragma unroll
      for (int r = 0; r < 4; ++r) scr[(locb + r) * 16 + l15] = (_Float16)h[r];
    }
    asm volatile("s_waitcnt lgkmcnt(0)" ::: "memory");   // wave-local DS order
    if (flagmode){
      // release: sc0 data stores (r9-proven) -> vmcnt ack (= at L2) ->
      // L2-local atomic inc (no sc1) -> sys flag sc0sc1 -> truth sc0sc1
      if (l < 16){
        int bl = l >> 1;
        int hc = l & 1;
        half8 ch = *(const half8*)&scr[bl * 16 + hc * 8];
        const char* df = fastb + (size_t)(t & mask) * GSLOT
                       + (size_t)bl * 1024 + (size_t)g * 32 + (size_t)hc * 16;
        asm volatile("global_store_dwordx4 %0, %1, off sc0"
                     :: "v"(df), "v"(ch) : "memory");
      }
      asm volatile("s_waitcnt vmcnt(0)" ::: "memory");   // data in XCD L2
      if (l == 0){
        int one = 1;
        int* cpub = ctr_l + ((grp * 512 + (t & mask)) << 4);
        asm volatile("global_atomic_add %0, %1, off"
                     :: "v"(cpub), "v"(one) : "memory");
        int pv = t + 1;
        asm volatile("global_store_dword %0, %1, off sc0 sc1"
                     :: "v"(fpub_s), "v"(pv) : "memory");
      }
      if (l < 16){
        int bl = l >> 1;
        int hc = l & 1;
        half8 ch = *(const half8*)&scr[bl * 16 + hc * 8];
        const char* dt = truth + (size_t)(t & mask) * TSLOT
                       + (size_t)(grp * GRPB + bl) * 1024
                       + (size_t)g * 32 + (size_t)hc * 16;
        asm volatile("global_store_dwordx4 %0, %1, off sc0 sc1"
                     :: "v"(dt), "v"(ch) : "memory");
      }
    } else {
      const int pubN = fast ? 16 : 32;
      if (l < pubN){
        int bl = l >> 1;
        int hc = l & 1;
        half8 ch = *(const half8*)&scr[bl * 16 + hc * 8];
        int gbatch = fast ? (grp * GRPB + bl) : (w * 16 + bl);
        const char* dt = truth + (size_t)(t & mask) * TSLOT
                       + (size_t)gbatch * 1024 + (size_t)g * 32 + (size_t)hc * 16;
        asm volatile("global_store_dwordx4 %0, %1, off sc0 sc1"
                     :: "v"(dt), "v"(ch) : "memory");
      }
      // 5) coarse progress publish (reuse mode only), ordered after restores
      if (reuse && ((t & 7) == 7)){
        asm volatile("s_waitcnt vmcnt(0)" ::: "memory");
        if (l == 0){
          int pv = t + 1;
          const int* pp = fast ? (prog + 128 + grp * 32 + g) : (prog + w * 32 + g);
          asm volatile("global_store_dword %0, %1, off sc0 sc1"
                       :: "v"(pp), "v"(pv) : "memory");
        }
      }
    }
  }
}

// --- K3: logits + log_softmax from truth slot (Lmax-1). 64 blocks x 64. ---
__global__ __launch_bounds__(64) void gru_out(
    const char* __restrict__ truth, const int* __restrict__ lengths,
    const float* __restrict__ wout, const float* __restrict__ bout,
    float* __restrict__ out, int depth)
{
  const int b = blockIdx.x, l = threadIdx.x;
  const int Lmax = lengths[0];
  const _Float16* h = (const _Float16*)(truth
      + (size_t)((Lmax - 1) & (depth - 1)) * TSLOT + (size_t)b * 1024);
  half8 hv = *(const half8*)(h + l * 8);
  float p[NOUT];
  #pragma unroll
  for (int o = 0; o < NOUT; ++o){
    const float* wr = wout + o * HID + l * 8;
    float a = 0.f;
    #pragma unroll
    for (int i = 0; i < 8; ++i) a += wr[i] * (float)hv[i];
    #pragma unroll
    for (int d = 32; d >= 1; d >>= 1) a += __shfl_down(a, d, 64);
    p[o] = a;
  }
  if (l == 0){
    float lg[NOUT], m = -1e30f;
    #pragma unroll
    for (int o = 0; o < NOUT; ++o){
      float v = p[o] + bout[o];
      if (!(v == v)) v = -1.0f;
      lg[o] = v; m = fmaxf(m, v);
    }
    float ssum = 0.f;
    #pragma unroll
    for (int o = 0; o < NOUT; ++o) ssum += __expf(lg[o] - m);
    float ls = __logf(ssum);
    #pragma unroll
    for (int o = 0; o < NOUT; ++o) out[b * NOUT + o] = lg[o] - m - ls;
  }
}

extern "C" void kernel_launch(void* const* d_in, const int* in_sizes, int n_in,
                              void* d_out, int out_size, void* d_ws, size_t ws_size,
                              hipStream_t stream) {
  (void)in_sizes; (void)n_in; (void)out_size;
  const int*   seq     = (const int*)d_in[0];
  const int*   lengths = (const int*)d_in[1];
  const float* emb     = (const float*)d_in[2];
  const float* w_ih    = (const float*)d_in[3];
  const float* w_hh    = (const float*)d_in[4];
  const float* b_ih    = (const float*)d_in[5];
  const float* b_hh    = (const float*)d_in[6];
  const float* w_out   = (const float*)d_in[7];
  const float* b_out   = (const float*)d_in[8];
  float*       outp    = (float*)d_out;

  // ring depth: largest power of two in [16, 512] such that both rings
  // (depth * 128 KiB) + prog/ctr (267 KiB) fit the workspace after xg.
  size_t avail = (ws_size > (size_t)XG_BYTES + 524288)
               ? ws_size - (size_t)XG_BYTES - 524288 : 0;
  int depth = 16;
  while (depth < 512 && ((size_t)(depth << 1) * RING2) <= avail) depth <<= 1;

  char* ws = (char*)d_ws;
  ushort_t* xg    = (ushort_t*)ws;                                 // 100,663,296 B
  char*     truth = ws + XG_BYTES;                                 // depth*65,536 B
  char*     fastr = truth + (size_t)depth * TSLOT;                 // depth*65,536 B
  int*      prog  = (int*)(fastr + (size_t)depth * TSLOT);         // 66,816 ints

  gru_init<<<depth * 32, 256, 0, stream>>>(truth, prog);
  dim3 g1(SEQL, G3 / 64);
  gru_xgates<<<g1, 256, 0, stream>>>(seq, emb, w_ih, b_ih, xg);
  gru_rec<<<256, 256, 0, stream>>>(xg, w_hh, b_hh, lengths, truth, fastr, prog, depth);
  gru_out<<<BATCH, 64, 0, stream>>>(truth, lengths, w_out, b_out, outp, depth);
}

// Round 10
// 2176.924 us; speedup vs baseline: 1.2711x; 1.0106x over previous
//
#include <hip/hip_runtime.h>

// ---------------------------------------------------------------------------
// SimpleGRU on MI355X (gfx950). Round 15: r10 skeleton minus per-step truth.
//   r9/r10/r13: three different gates, identical 3.88us/step -> gate is not
//   the critical path. Invariant suspect: 16 fire-and-forget sc0sc1 truth
//   stores/step, whose fabric drain serializes into the next step's first
//   vmcnt(0) (waitcnt retires in issue order). r14 tested this but swapped in
//   an UNPROVEN L2-atomic gate with an unbounded poll -> hang -> container
//   died. r15 keeps r10's PROVEN sc0sc1 flag gate verbatim and changes ONE
//   thing: no truth stores in the loop (1 flag store remains). Final h is
//   written to the truth slot once, post-loop, for K3.
//   Sentinel fallback (truth now stale): bounded atomic-returning re-read of
//   the fast ring — gate release (flag after vmcnt(0)) => data is in this
//   XCD's L2; atomics execute at L2, bypass L1 (the only proven staleness
//   mechanism) => first round returns real data. Hard bound 100k rounds.
//   Unbalanced dispatch / small ws -> unchanged legacy r6 paths.
// ws: xg bf16 [512][1536][64] | truth [depth][64][512] f16 |
//     fast [8][depth][8][512] f16 | prog int[768]
// ---------------------------------------------------------------------------

typedef unsigned short ushort_t;
typedef short short8      __attribute__((ext_vector_type(8)));
typedef float floatx4     __attribute__((ext_vector_type(4)));
typedef unsigned int uintx4 __attribute__((ext_vector_type(4)));
typedef unsigned short ushort4v __attribute__((ext_vector_type(4)));
typedef _Float16 half8    __attribute__((ext_vector_type(8)));

#define SEQL 512
#define BATCH 64
#define EMBD 256
#define HID 512
#define G3 1536
#define NOUT 5
#define NGRP 8                     // one group per XCD (fast mode)
#define GRPB 8                     // batches per group (fast mode)
#define GSLOT 8192                 // fast ring slot: 8 x 512 x 2B
#define TSLOT 65536                // truth ring slot: 64 x 512 x 2B
#define RING2 131072               // truth + fast bytes per depth unit
#define XG_BYTES 100663296
#define PROGN 512                  // legacy prog area (includes regs at 384)
#define FLAGN 256                  // flag_s[8][32]
#define ZERON (PROGN + FLAGN)      // 768 ints zeroed by init
#define REREAD_BOUND 100000

__device__ __forceinline__ float bf2f(ushort_t v){
  union { unsigned u; float f; } x; x.u = ((unsigned)v) << 16; return x.f;
}
__device__ __forceinline__ ushort_t f2bf(float f){
  unsigned u = __float_as_uint(f);
  return (ushort_t)((u + 0x7FFFu + ((u >> 16) & 1u)) >> 16);
}
__device__ __forceinline__ float sigm(float x){
  x = fminf(fmaxf(x, -20.f), 20.f);
  return 1.f / (1.f + __expf(-x));
}
__device__ __forceinline__ float tanh_c(float x){
  x = fminf(fmaxf(x, -10.f), 10.f);
  float e = __expf(2.f * x);
  return (e - 1.f) / (e + 1.f);
}
__device__ __forceinline__ bool has_sent(half8 v){
  union { half8 h; unsigned u[4]; } x; x.h = v;
  bool b = false;
  #pragma unroll
  for (int i = 0; i < 4; ++i){
    b |= ((x.u[i] & 0xFFFFu) == 0xFFFFu);
    b |= ((x.u[i] >> 16) == 0xFFFFu);
  }
  return b;
}

// --- K0: sentinel-fill both rings at SYSTEM scope; zero prog+flags. ---
__global__ __launch_bounds__(256) void gru_init(char* __restrict__ rings,
                                                int* __restrict__ prog){
  size_t i = ((size_t)blockIdx.x * 256 + threadIdx.x) * 16;
  uintx4 s = {0xFFFFFFFFu, 0xFFFFFFFFu, 0xFFFFFFFFu, 0xFFFFFFFFu};
  const char* p = rings + i;
  asm volatile("global_store_dwordx4 %0, %1, off sc0 sc1" :: "v"(p), "v"(s) : "memory");
  if (blockIdx.x == 0){
    int z = 0;
    for (int k = threadIdx.x; k < ZERON; k += 256){
      asm volatile("global_store_dword %0, %1, off sc0 sc1"
                   :: "v"(prog + k), "v"(z) : "memory");
    }
  }
}

// --- K1: x_gates = emb[seq] @ w_ih^T + b_ih, bf16, layout [s][1536][64] ---
#define LDSIDX2(row, chunk) (((row) << 7) + ((((chunk) ^ ((row) & 7))) << 3))
__global__ __launch_bounds__(256) void gru_xgates(
    const int* __restrict__ seq, const float* __restrict__ emb,
    const float* __restrict__ w_ih, const float* __restrict__ b_ih,
    ushort_t* __restrict__ xg)
{
  __shared__ __align__(16) short lA[64 * 128];
  __shared__ __align__(16) short lB[64 * 128];
  const int tid   = threadIdx.x;
  const int sIdx  = blockIdx.x;
  const int nBase = blockIdx.y * 64;
  const int w    = tid >> 6;
  const int l    = tid & 63;
  const int l15  = l & 15;
  const int quad = l >> 4;
  floatx4 acc[4] = {};

  #pragma unroll
  for (int kp = 0; kp < 2; ++kp){
    __syncthreads();
    #pragma unroll
    for (int i = 0; i < 4; ++i){
      int lin = i * 256 + tid;
      int row = lin >> 4;
      int kc  = lin & 15;
      int kbase = kp * 128 + kc * 8;
      int token = seq[(sIdx << 6) + row];
      const float* srcA = emb  + (size_t)token * EMBD + kbase;
      const float* srcB = w_ih + (size_t)(nBase + row) * EMBD + kbase;
      floatx4 a0 = *(const floatx4*)(srcA);
      floatx4 a1 = *(const floatx4*)(srcA + 4);
      floatx4 b0 = *(const floatx4*)(srcB);
      floatx4 b1 = *(const floatx4*)(srcB + 4);
      short8 pa, pb;
      #pragma unroll
      for (int j = 0; j < 4; ++j){
        pa[j]     = (short)f2bf(a0[j]);
        pa[j + 4] = (short)f2bf(a1[j]);
        pb[j]     = (short)f2bf(b0[j]);
        pb[j + 4] = (short)f2bf(b1[j]);
      }
      *(short8*)&lA[LDSIDX2(row, kc)] = pa;
      *(short8*)&lB[LDSIDX2(row, kc)] = pb;
    }
    __syncthreads();
    #pragma unroll
    for (int kc = 0; kc < 4; ++kc){
      int chunk = kc * 4 + quad;
      short8 a = *(const short8*)&lA[LDSIDX2(w * 16 + l15, chunk)];
      #pragma unroll
      for (int s = 0; s < 4; ++s){
        short8 bf = *(const short8*)&lB[LDSIDX2(s * 16 + l15, chunk)];
        acc[s] = __builtin_amdgcn_mfma_f32_16x16x32_bf16(a, bf, acc[s], 0, 0, 0);
      }
    }
  }
  #pragma unroll
  for (int s = 0; s < 4; ++s){
    int g = nBase + s * 16 + l15;
    float bias = b_ih[g];
    ushort4v pk;
    #pragma unroll
    for (int r = 0; r < 4; ++r) pk[r] = f2bf(acc[s][r] + bias);
    *(ushort4v*)(xg + ((size_t)sIdx * G3 + g) * BATCH + (w * 16 + quad * 4)) = pk;
  }
}

// --- K2: recurrence. 256 blocks x 256 threads. ---
__global__ __launch_bounds__(256, 1) void gru_rec(
    const ushort_t* __restrict__ xg, const float* __restrict__ whh,
    const float* __restrict__ bhh, const int* __restrict__ lengths,
    char* __restrict__ truth, char* __restrict__ fastr,
    int* __restrict__ prog, int depth)
{
  __shared__ __align__(16) _Float16 wlds[48 * 64 * 8];   // 49,152 B (B-frags)
  __shared__ __align__(16) _Float16 hscr[4 * 256];       //  2,048 B (repack)
  __shared__ int s_grp, s_slc, s_fast;
  const int tid  = threadIdx.x;
  const int w    = tid >> 6;
  const int l    = tid & 63;
  const int l15  = l & 15;
  const int quad = l >> 4;
  int* flags_s = prog + PROGN;           // [NGRP][32] system-scope flags

  // ---- rendezvous + XCD-affinity group formation ----
  int* regs = prog + 384;              // [0]=gcount, [1..8]=per-XCD counts
  if (tid == 0){
    unsigned xcd;
    asm volatile("s_getreg_b32 %0, hwreg(HW_REG_XCC_ID)" : "=s"(xcd));
    xcd &= 7u;
    int myx = atomicAdd(&regs[1 + xcd], 1);
    asm volatile("s_waitcnt vmcnt(0)" ::: "memory");  // xcd count visible first
    int gt = atomicAdd(&regs[0], 1);
    int v;
    do {
      asm volatile("s_sleep 1" ::: "memory");
      asm volatile("global_load_dword %0, %1, off sc0 sc1\n\t"
                   "s_waitcnt vmcnt(0)"
                   : "=v"(v) : "v"(&regs[0]) : "memory");
    } while (v < 256);
    int ok = 1;
    #pragma unroll
    for (int x = 0; x < 8; ++x){
      int c;
      asm volatile("global_load_dword %0, %1, off sc0 sc1\n\t"
                   "s_waitcnt vmcnt(0)"
                   : "=v"(c) : "v"(&regs[1 + x]) : "memory");
      ok &= (c == 32);
    }
    s_fast = ok;
    s_grp  = ok ? (int)xcd : 0;
    s_slc  = ok ? (myx & 31) : gt;
  }
  __syncthreads();
  const int fast = s_fast;
  const int grp  = s_grp;
  const int g0   = s_slc;
  if (!fast && g0 >= 32) return;       // fallback: only 32 blocks participate
  const int g = g0 & 31;               // hidden slice [g*16, g*16+16)
  const int j = g * 16 + l15;          // this lane's hidden unit

  // ---- setup: 48 W_hh rows f32->f16 into B-frag LDS (all 4 waves) ----
  #pragma unroll
  for (int i = 0; i < 12; ++i){
    int p  = i * 4 + w;                 // 0..47
    int G  = p >> 4;                    // gate (0=r,1=z,2=n)
    int ks = p & 15;                    // K-step
    const float* src = whh + (size_t)(G * HID + j) * HID + ks * 32 + quad * 8;
    floatx4 f0 = *(const floatx4*)(src);
    floatx4 f1 = *(const floatx4*)(src + 4);
    half8 hv;
    #pragma unroll
    for (int q = 0; q < 4; ++q){ hv[q] = (_Float16)f0[q]; hv[q + 4] = (_Float16)f1[q]; }
    *(half8*)&wlds[((size_t)p * 64 + l) * 8] = hv;
  }
  __syncthreads();
  if (fast && tid >= 64) return;       // fast mode: wave 0 runs alone

  char* fastb = fastr + (size_t)grp * depth * GSLOT;
  const int locb = fast ? ((quad & 1) * 4) : (quad * 4);  // wave-local batch base
  const int gb   = fast ? (grp * GRPB + locb) : (w * 16 + locb);  // global batch
  const int arow = l15 & 7;                                // fast ring A-row
  const int trow = fast ? (grp * GRPB + (l15 & 7)) : (w * 16 + l15); // truth row
  const float bhR = bhh[j], bhZ = bhh[HID + j], bhN = bhh[2 * HID + j];
  int   len[4];
  float h[4];
  #pragma unroll
  for (int r = 0; r < 4; ++r){ len[r] = lengths[gb + r]; h[r] = 0.f; }
  const int Lmax  = lengths[0];        // global max: all blocks run to Lmax
  const int mask  = depth - 1;
  const bool reuse = (depth < Lmax);
  const int flagmode = fast && !reuse; // no-truth fast protocol
  const int* fpoll_s = flags_s + grp * 32 + (l & 31);
  int* fpub_s = flags_s + grp * 32 + g;
  int cmin = 0;

  for (int t = 0; t < Lmax; ++t){
    // 0) ring-reuse guard (legacy modes only; dead when depth >= Lmax)
    if (reuse && t >= depth){
      int target = t - depth + 2;
      if (cmin < target){
        int tgt2 = target + 4;
        if (fast){
          const int* pp = prog + 128 + grp * 32 + (l & 31);
          while (true){
            int p0;
            asm volatile("global_load_dword %0, %1, off sc0 sc1\n\t"
                         "s_waitcnt vmcnt(0)"
                         : "=v"(p0) : "v"(pp) : "memory");
            if (__all(p0 >= tgt2)) break;
            __builtin_amdgcn_s_sleep(2);
          }
        } else {
          while (true){
            int p0, p1;
            asm volatile("global_load_dword %0, %2, off sc0 sc1\n\t"
                         "global_load_dword %1, %3, off sc0 sc1\n\t"
                         "s_waitcnt vmcnt(0)"
                         : "=v"(p0), "=v"(p1) : "v"(prog + l), "v"(prog + 64 + l)
                         : "memory");
            if (__all(p0 >= tgt2 && p1 >= tgt2)) break;
            __builtin_amdgcn_s_sleep(2);
          }
        }
        cmin = tgt2;
      }
    }

    // 1) xg prefetch (independent of h)
    const ushort_t* xt = xg + (size_t)t * G3 * BATCH;
    ushort4v xR = __builtin_nontemporal_load(
        (const ushort4v*)(xt + (size_t)(          j) * BATCH + gb));
    ushort4v xZ = __builtin_nontemporal_load(
        (const ushort4v*)(xt + (size_t)(HID     + j) * BATCH + gb));
    ushort4v xN = __builtin_nontemporal_load(
        (const ushort4v*)(xt + (size_t)(2 * HID + j) * BATCH + gb));

    // 2) consume h(t-1)
    floatx4 aR = {0.f,0.f,0.f,0.f}, aZ = {0.f,0.f,0.f,0.f}, aN = {0.f,0.f,0.f,0.f};
    if (t > 0){
      const int slotp = (t - 1) & mask;
      const char* rowf = fastb + (size_t)slotp * GSLOT
                       + (size_t)arow * 1024 + quad * 16;
      const char* rowt = truth + (size_t)slotp * TSLOT
                       + (size_t)trow * 1024 + quad * 16;
      half8 aF[16];
      if (flagmode){
        // 2a: r10-PROVEN sc0sc1 flag gate (producers always publish; the
        //     gate provably terminates — ran 512 steps x 256 blocks in r10)
        int miss = 0;
        while (true){
          int fv;
          asm volatile("global_load_dword %0, %1, off sc0 sc1\n\t"
                       "s_waitcnt vmcnt(0)"
                       : "=v"(fv) : "v"(fpoll_s) : "memory");
          if (__all(fv >= t)) break;
          ++miss;
          if (miss > 64) __builtin_amdgcn_s_sleep(8);
          else           __builtin_amdgcn_s_sleep(1);
        }
        // 2b: one-shot sc0 data read (first touch by this block each step;
        //     flag release happens after the producer's vmcnt(0) ack, so the
        //     data is resident in this XCD's L2)
        #pragma unroll
        for (int ks = 0; ks < 16; ++ks){
          const char* pa = rowf + ks * 64;
          asm volatile("global_load_dwordx4 %0, %1, off sc0"
                       : "=v"(aF[ks]) : "v"(pa) : "memory");
        }
        asm volatile("s_waitcnt vmcnt(0)"
                     : "+v"(aF[0]),  "+v"(aF[1]),  "+v"(aF[2]),  "+v"(aF[3]),
                       "+v"(aF[4]),  "+v"(aF[5]),  "+v"(aF[6]),  "+v"(aF[7]),
                       "+v"(aF[8]),  "+v"(aF[9]),  "+v"(aF[10]), "+v"(aF[11]),
                       "+v"(aF[12]), "+v"(aF[13]), "+v"(aF[14]), "+v"(aF[15])
                     :: "memory");
        bool bad = false;
        #pragma unroll
        for (int ks = 0; ks < 16; ++ks) bad |= has_sent(aF[ks]);
        if (__any(bad)){
          // bounded L1-proof re-read: atomics execute at L2, bypass L1 (the
          // only proven staleness mechanism); data is L2-resident by the
          // release argument, so round 1 should already return real data.
          for (int ks = 0; ks < 16; ++ks){
            if (!has_sent(aF[ks])) continue;
            union { unsigned u[4]; half8 hh; } cvt;
            const unsigned* wp = (const unsigned*)(rowf + ks * 64);
            for (int d = 0; d < 4; ++d){
              unsigned v = 0; int rounds = 0;
              while (rounds++ < REREAD_BOUND){
                int zro = 0;
                asm volatile("global_atomic_add %0, %1, %2, off sc0\n\t"
                             "s_waitcnt vmcnt(0)"
                             : "=v"(v) : "v"(wp + d), "v"(zro) : "memory");
                if ((v & 0xFFFFu) != 0xFFFFu && (v >> 16) != 0xFFFFu) break;
                __builtin_amdgcn_s_sleep(2);
              }
              cvt.u[d] = v;
            }
            aF[ks] = cvt.hh;
          }
        }
      } else {
        // legacy: self-synchronizing sentinel poll on truth (r6-proven)
        int rounds = 0;
        while (true){
          if (rounds){
            if (rounds > 64) __builtin_amdgcn_s_sleep(8);
            else             __builtin_amdgcn_s_sleep(2);
          }
          ++rounds;
          #pragma unroll
          for (int ks = 0; ks < 16; ++ks){
            const char* pa = rowt + ks * 64;
            asm volatile("global_load_dwordx4 %0, %1, off sc0 sc1"
                         : "=v"(aF[ks]) : "v"(pa) : "memory");
          }
          asm volatile("s_waitcnt vmcnt(0)"
                       : "+v"(aF[0]),  "+v"(aF[1]),  "+v"(aF[2]),  "+v"(aF[3]),
                         "+v"(aF[4]),  "+v"(aF[5]),  "+v"(aF[6]),  "+v"(aF[7]),
                         "+v"(aF[8]),  "+v"(aF[9]),  "+v"(aF[10]), "+v"(aF[11]),
                         "+v"(aF[12]), "+v"(aF[13]), "+v"(aF[14]), "+v"(aF[15])
                       :: "memory");
          bool bad = false;
          #pragma unroll
          for (int ks = 0; ks < 16; ++ks) bad |= has_sent(aF[ks]);
          if (!__any(bad)) break;
        }
      }
      #pragma unroll
      for (int ks = 0; ks < 16; ++ks){
        half8 a  = aF[ks];
        half8 b0 = *(const half8*)&wlds[((size_t)(0 * 16 + ks) * 64 + l) * 8];
        half8 b1 = *(const half8*)&wlds[((size_t)(1 * 16 + ks) * 64 + l) * 8];
        half8 b2 = *(const half8*)&wlds[((size_t)(2 * 16 + ks) * 64 + l) * 8];
        aR = __builtin_amdgcn_mfma_f32_16x16x32_f16(a, b0, aR, 0, 0, 0);
        aZ = __builtin_amdgcn_mfma_f32_16x16x32_f16(a, b1, aZ, 0, 0, 0);
        aN = __builtin_amdgcn_mfma_f32_16x16x32_f16(a, b2, aN, 0, 0, 0);
      }
      // restore sentinels on consumed truth chunks (legacy reuse only)
      if (reuse){
        uintx4 sv = {0xFFFFFFFFu, 0xFFFFFFFFu, 0xFFFFFFFFu, 0xFFFFFFFFu};
        if (!fast || l15 < 8){
          #pragma unroll
          for (int ks = 0; ks < 16; ++ks){
            const char* pt = rowt + ks * 64;
            asm volatile("global_store_dwordx4 %0, %1, off sc0 sc1"
                         :: "v"(pt), "v"(sv) : "memory");
          }
        }
      }
    }

    // 3) gates + h update (f32 carry); mirrored quads duplicate harmlessly
    #pragma unroll
    for (int r = 0; r < 4; ++r){
      float rr = sigm(bf2f(xR[r]) + aR[r] + bhR);
      float zz = sigm(bf2f(xZ[r]) + aZ[r] + bhZ);
      float nn = tanh_c(bf2f(xN[r]) + rr * (aN[r] + bhN));
      float hn = (1.f - zz) * nn + zz * h[r];
      h[r] = (t < len[r]) ? hn : h[r];
    }

    // 4) intra-wave repack via LDS, then publish h(t)
    _Float16* scr = hscr + w * 256;
    if (!fast || quad < 2){
      #pragma unroll
      for (int r = 0; r < 4; ++r) scr[(locb + r) * 16 + l15] = (_Float16)h[r];
    }
    asm volatile("s_waitcnt lgkmcnt(0)" ::: "memory");   // wave-local DS order
    if (flagmode){
      // release: 16 sc0 fast stores -> vmcnt ack (data in this XCD's L2) ->
      // ONE sc0sc1 flag store. NO truth stores in the loop (the r15 delta).
      if (l < 16){
        int bl = l >> 1;
        int hc = l & 1;
        half8 ch = *(const half8*)&scr[bl * 16 + hc * 8];
        const char* df = fastb + (size_t)(t & mask) * GSLOT
                       + (size_t)bl * 1024 + (size_t)g * 32 + (size_t)hc * 16;
        asm volatile("global_store_dwordx4 %0, %1, off sc0"
                     :: "v"(df), "v"(ch) : "memory");
      }
      asm volatile("s_waitcnt vmcnt(0)" ::: "memory");   // data in XCD L2
      if (l == 0){
        int pv = t + 1;
        asm volatile("global_store_dword %0, %1, off sc0 sc1"
                     :: "v"(fpub_s), "v"(pv) : "memory");
      }
    } else {
      const int pubN = fast ? 16 : 32;
      if (l < pubN){
        int bl = l >> 1;
        int hc = l & 1;
        half8 ch = *(const half8*)&scr[bl * 16 + hc * 8];
        int gbatch = fast ? (grp * GRPB + bl) : (w * 16 + bl);
        const char* dt = truth + (size_t)(t & mask) * TSLOT
                       + (size_t)gbatch * 1024 + (size_t)g * 32 + (size_t)hc * 16;
        asm volatile("global_store_dwordx4 %0, %1, off sc0 sc1"
                     :: "v"(dt), "v"(ch) : "memory");
      }
      // 5) coarse progress publish (reuse mode only), ordered after restores
      if (reuse && ((t & 7) == 7)){
        asm volatile("s_waitcnt vmcnt(0)" ::: "memory");
        if (l == 0){
          int pv = t + 1;
          const int* pp = fast ? (prog + 128 + grp * 32 + g) : (prog + w * 32 + g);
          asm volatile("global_store_dword %0, %1, off sc0 sc1"
                       :: "v"(pp), "v"(pv) : "memory");
        }
      }
    }
  }

  // ---- post-loop (flagmode): publish final h ONCE (sc0 sc1) to the truth
  //      slot K3 reads. scr holds h(Lmax-1) from the last iteration. ----
  if (flagmode && l < 16){
    _Float16* scr = hscr + w * 256;
    int bl = l >> 1;
    int hc = l & 1;
    half8 ch = *(const half8*)&scr[bl * 16 + hc * 8];
    const char* dt = truth + (size_t)((Lmax - 1) & mask) * TSLOT
                   + (size_t)(grp * GRPB + bl) * 1024
                   + (size_t)g * 32 + (size_t)hc * 16;
    asm volatile("global_store_dwordx4 %0, %1, off sc0 sc1"
                 :: "v"(dt), "v"(ch) : "memory");
  }
}

// --- K3: logits + log_softmax from truth slot (Lmax-1). 64 blocks x 64. ---
__global__ __launch_bounds__(64) void gru_out(
    const char* __restrict__ truth, const int* __restrict__ lengths,
    const float* __restrict__ wout, const float* __restrict__ bout,
    float* __restrict__ out, int depth)
{
  const int b = blockIdx.x, l = threadIdx.x;
  const int Lmax = lengths[0];
  const _Float16* h = (const _Float16*)(truth
      + (size_t)((Lmax - 1) & (depth - 1)) * TSLOT + (size_t)b * 1024);
  half8 hv = *(const half8*)(h + l * 8);
  float p[NOUT];
  #pragma unroll
  for (int o = 0; o < NOUT; ++o){
    const float* wr = wout + o * HID + l * 8;
    float a = 0.f;
    #pragma unroll
    for (int i = 0; i < 8; ++i) a += wr[i] * (float)hv[i];
    #pragma unroll
    for (int d = 32; d >= 1; d >>= 1) a += __shfl_down(a, d, 64);
    p[o] = a;
  }
  if (l == 0){
    float lg[NOUT], m = -1e30f;
    #pragma unroll
    for (int o = 0; o < NOUT; ++o){
      float v = p[o] + bout[o];
      if (!(v == v)) v = -1.0f;
      lg[o] = v; m = fmaxf(m, v);
    }
    float ssum = 0.f;
    #pragma unroll
    for (int o = 0; o < NOUT; ++o) ssum += __expf(lg[o] - m);
    float ls = __logf(ssum);
    #pragma unroll
    for (int o = 0; o < NOUT; ++o) out[b * NOUT + o] = lg[o] - m - ls;
  }
}

extern "C" void kernel_launch(void* const* d_in, const int* in_sizes, int n_in,
                              void* d_out, int out_size, void* d_ws, size_t ws_size,
                              hipStream_t stream) {
  (void)in_sizes; (void)n_in; (void)out_size;
  const int*   seq     = (const int*)d_in[0];
  const int*   lengths = (const int*)d_in[1];
  const float* emb     = (const float*)d_in[2];
  const float* w_ih    = (const float*)d_in[3];
  const float* w_hh    = (const float*)d_in[4];
  const float* b_ih    = (const float*)d_in[5];
  const float* b_hh    = (const float*)d_in[6];
  const float* w_out   = (const float*)d_in[7];
  const float* b_out   = (const float*)d_in[8];
  float*       outp    = (float*)d_out;

  // ring depth: largest power of two in [16, 512] such that both rings
  // (depth * 128 KiB) + prog fit the workspace after xg.
  size_t avail = (ws_size > (size_t)XG_BYTES + 32768)
               ? ws_size - (size_t)XG_BYTES - 32768 : 0;
  int depth = 16;
  while (depth < 512 && ((size_t)(depth << 1) * RING2) <= avail) depth <<= 1;

  char* ws = (char*)d_ws;
  ushort_t* xg    = (ushort_t*)ws;                                 // 100,663,296 B
  char*     truth = ws + XG_BYTES;                                 // depth*65,536 B
  char*     fastr = truth + (size_t)depth * TSLOT;                 // depth*65,536 B
  int*      prog  = (int*)(fastr + (size_t)depth * TSLOT);         // 768 ints

  gru_init<<<depth * 32, 256, 0, stream>>>(truth, prog);
  dim3 g1(SEQL, G3 / 64);
  gru_xgates<<<g1, 256, 0, stream>>>(seq, emb, w_ih, b_ih, xg);
  gru_rec<<<256, 256, 0, stream>>>(xg, w_hh, b_hh, lengths, truth, fastr, prog, depth);
  gru_out<<<BATCH, 64, 0, stream>>>(truth, lengths, w_out, b_out, outp, depth);
}